// Round 4
// baseline (1889.227 us; speedup 1.0000x reference)
//
#include <hip/hip_runtime.h>
#include <hip/hip_bf16.h>

typedef unsigned short u16;
typedef unsigned int   u32;
typedef unsigned char  u8;

typedef __attribute__((ext_vector_type(8))) short bf16x8;
typedef __attribute__((ext_vector_type(4))) float f32x4;
typedef __attribute__((ext_vector_type(16))) float f32x16;

static __device__ __forceinline__ float bf2f(u16 u){ return __uint_as_float(((u32)u)<<16); }
static __device__ __forceinline__ u16 f2bf(float f){
  u32 u = __float_as_uint(f);
  u32 r = (u + 0x7fff + ((u>>16)&1)) >> 16;   // RNE; inputs finite
  return (u16)r;
}

// fp8 e4m3 (OCP) helpers — HW cvt, saturating via pre-clamp
static __device__ __forceinline__ u8 f2fp8(float v){
  v = fminf(440.f, fmaxf(-440.f, v));
  return (u8)(__builtin_amdgcn_cvt_pk_fp8_f32(v, 0.f, 0, false) & 0xff);
}
static __device__ __forceinline__ u32 pk4_fp8(float a, float b, float c, float d){
  int w = __builtin_amdgcn_cvt_pk_fp8_f32(a, b, 0, false);
  w = __builtin_amdgcn_cvt_pk_fp8_f32(c, d, w, true);
  return (u32)w;
}

static __device__ __forceinline__ f32x4 mfma_bf16(bf16x8 a, bf16x8 b, f32x4 c){
  return __builtin_amdgcn_mfma_f32_16x16x32_bf16(a, b, c, 0, 0, 0);
}
static __device__ __forceinline__ f32x4 mfma_fp8(long a, long b, f32x4 c){
  return __builtin_amdgcn_mfma_f32_16x16x32_fp8_fp8(a, b, c, 0, 0, 0);
}
static __device__ __forceinline__ f32x16 mfma_fp8_32(long a, long b, f32x16 c){
  return __builtin_amdgcn_mfma_f32_32x32x16_fp8_fp8(a, b, c, 0, 0, 0);
}
static __device__ __forceinline__ long lo64(uint4 v){ return (long)(((unsigned long long)v.y<<32) | v.x); }
static __device__ __forceinline__ long hi64(uint4 v){ return (long)(((unsigned long long)v.w<<32) | v.z); }

// ---------------------------------------------------------------------------
// K-w8: W f32 [m][k] -> fp8 packed for 32x32x16 B-fragments.
// Layout: 1KB block per (pt = m/64, kt = k/32, mcp = (m/32)&1):
//   addr = ((pt*64 + kt)*2 + mcp)*1024 + lane*16 + sel*8 + j
//   element = W[pt*64 + (mcp*2+sel)*16 + (lane>>5)*8 + j][kt*32 + (lane&31)]
// grid (32,32,2), block 256.
// ---------------------------------------------------------------------------
__global__ void k_w8(const float* __restrict__ Wc, const float* __restrict__ Wd,
                     u8* __restrict__ Wc8, u8* __restrict__ Wd8){
  __shared__ float tile[64][65];
  const float* src = blockIdx.z ? Wd : Wc;
  u8* dst = blockIdx.z ? Wd8 : Wc8;
  const int m0 = blockIdx.x*64, k0 = blockIdx.y*64;
  const int t = threadIdx.x, r = t & 63, cc = t >> 6;
  #pragma unroll
  for (int j=0;j<4;j++){
    float4 v = *(const float4*)&src[(size_t)(m0+r)*2048 + k0 + cc*16 + j*4];
    tile[r][cc*16+j*4+0]=v.x; tile[r][cc*16+j*4+1]=v.y;
    tile[r][cc*16+j*4+2]=v.z; tile[r][cc*16+j*4+3]=v.w;
  }
  __syncthreads();
  const int lane = t & 63, sub = t >> 6;     // sub 0..3
  const int kth = sub & 1, mcp = sub >> 1;
  const int kl = kth*32 + (lane & 31);       // k within 64-tile
  const int ml = mcp*32 + (lane >> 5)*8;     // m base within 64-tile
  u32 b0 = pk4_fp8(16.f*tile[ml+ 0][kl], 16.f*tile[ml+ 1][kl], 16.f*tile[ml+ 2][kl], 16.f*tile[ml+ 3][kl]);
  u32 b1 = pk4_fp8(16.f*tile[ml+ 4][kl], 16.f*tile[ml+ 5][kl], 16.f*tile[ml+ 6][kl], 16.f*tile[ml+ 7][kl]);
  u32 b2 = pk4_fp8(16.f*tile[ml+16][kl], 16.f*tile[ml+17][kl], 16.f*tile[ml+18][kl], 16.f*tile[ml+19][kl]);
  u32 b3 = pk4_fp8(16.f*tile[ml+20][kl], 16.f*tile[ml+21][kl], 16.f*tile[ml+22][kl], 16.f*tile[ml+23][kl]);
  const int pt = m0 >> 6, kt = (k0 >> 5) + kth;
  u8* dbase = dst + (size_t)((pt*64 + kt)*2 + mcp)*1024 + lane*16;
  *(uint4*)dbase = make_uint4(b0, b1, b2, b3);
}

// ---------------------------------------------------------------------------
// K-hcvt: h f32 [b][m][64] -> hb16 (bf16 row-major), hfm (bf16 frag-major B for
// phase 1), ht8p (fp8 frag-major B for phase 4). grid (32,16), block 256.
// ---------------------------------------------------------------------------
__global__ void k_hcvt(const float* __restrict__ h, u16* __restrict__ hb16,
                       u8* __restrict__ ht8p, u16* __restrict__ hfm){
  __shared__ float tile[64][65];
  const int k0 = blockIdx.x*64, b = blockIdx.y;
  const int t = threadIdx.x, r = t & 63, cc = t >> 6;
  const float* src = h + ((size_t)b*2048 + k0)*64;
  u32 hw[8];
  #pragma unroll
  for (int j=0;j<4;j++){
    float4 v = *(const float4*)&src[(size_t)r*64 + cc*16 + j*4];
    tile[r][cc*16+j*4+0]=v.x; tile[r][cc*16+j*4+1]=v.y;
    tile[r][cc*16+j*4+2]=v.z; tile[r][cc*16+j*4+3]=v.w;
    hw[2*j]   = (u32)f2bf(v.x) | ((u32)f2bf(v.y)<<16);
    hw[2*j+1] = (u32)f2bf(v.z) | ((u32)f2bf(v.w)<<16);
  }
  u16* hp = hb16 + (((size_t)b*2048 + k0 + r)*64 + cc*16);
  *(uint4*)hp     = make_uint4(hw[0],hw[1],hw[2],hw[3]);
  *(uint4*)(hp+8) = make_uint4(hw[4],hw[5],hw[6],hw[7]);
  __syncthreads();
  {
    u32 f0 = pk4_fp8(tile[cc*16+ 0][r], tile[cc*16+ 1][r], tile[cc*16+ 2][r], tile[cc*16+ 3][r]);
    u32 f1 = pk4_fp8(tile[cc*16+ 4][r], tile[cc*16+ 5][r], tile[cc*16+ 6][r], tile[cc*16+ 7][r]);
    u32 f2 = pk4_fp8(tile[cc*16+ 8][r], tile[cc*16+ 9][r], tile[cc*16+10][r], tile[cc*16+11][r]);
    u32 f3 = pk4_fp8(tile[cc*16+12][r], tile[cc*16+13][r], tile[cc*16+14][r], tile[cc*16+15][r]);
    const int pt = k0 >> 6, half = cc >> 1, q0 = (cc & 1)*2;
    const int ctg = r >> 4, lcv = r & 15;
    u8* dbase = ht8p + (size_t)b*131072 + (size_t)((pt*4 + ctg)*64)*16 + half*8;
    *(uint2*)(dbase + (q0*16 + lcv)*16)     = make_uint2(f0, f1);
    *(uint2*)(dbase + ((q0+1)*16 + lcv)*16) = make_uint2(f2, f3);
  }
  {
    const int col = k0 + r, ks = cc >> 1, q0 = (cc & 1)*2;
    const int ctg = col >> 4, lcv = col & 15;
    u16* fbase = hfm + (size_t)b*131072 + (size_t)ks*65536 + ((size_t)ctg*64)*8;
    #pragma unroll
    for (int qq=0; qq<2; ++qq){
      int q = q0 + qq;
      u32 p0 = (u32)f2bf(tile[r][ks*32+q*8+0]) | ((u32)f2bf(tile[r][ks*32+q*8+1])<<16);
      u32 p1 = (u32)f2bf(tile[r][ks*32+q*8+2]) | ((u32)f2bf(tile[r][ks*32+q*8+3])<<16);
      u32 p2 = (u32)f2bf(tile[r][ks*32+q*8+4]) | ((u32)f2bf(tile[r][ks*32+q*8+5])<<16);
      u32 p3 = (u32)f2bf(tile[r][ks*32+q*8+6]) | ((u32)f2bf(tile[r][ks*32+q*8+7])<<16);
      *(uint4*)(fbase + (size_t)(q*16 + lcv)*8) = make_uint4(p0,p1,p2,p3);
    }
  }
}

// ---------------------------------------------------------------------------
// K1: row n of A = E E^T. sign-mask (1 pos, 2 neg) + P=softmax(relu) bf16.
// ---------------------------------------------------------------------------
__global__ void k_P(const float* __restrict__ E, u16* __restrict__ P, u8* __restrict__ msk){
  __shared__ float Ew[16];
  __shared__ float arow[2048];
  __shared__ float red[4];
  const int t = threadIdx.x, n = blockIdx.x;
  if (t < 16) Ew[t] = E[n*16 + t];
  __syncthreads();
  float lmax = 0.f;
  for (int i=0;i<8;i++){
    int m = t + 256*i;
    const float* ep = E + m*16;
    float dot = 0.f;
    #pragma unroll
    for (int d=0; d<16; ++d) dot += Ew[d]*ep[d];
    msk[n*2048 + m] = dot > 0.f ? (u8)1 : (dot < 0.f ? (u8)2 : (u8)0);
    float ar = fmaxf(dot, 0.f);
    arow[m] = ar;
    lmax = fmaxf(lmax, ar);
  }
  for (int o=1;o<64;o<<=1) lmax = fmaxf(lmax, __shfl_xor(lmax, o));
  if ((t&63)==0) red[t>>6] = lmax;
  __syncthreads();
  float gmax = fmaxf(fmaxf(red[0],red[1]), fmaxf(red[2],red[3]));
  __syncthreads();
  float lsum = 0.f;
  for (int i=0;i<8;i++){
    int m = t + 256*i;
    float e = expf(arow[m] - gmax);
    arow[m] = e;
    lsum += e;
  }
  for (int o=1;o<64;o<<=1) lsum += __shfl_xor(lsum, o);
  if ((t&63)==0) red[t>>6] = lsum;
  __syncthreads();
  float inv = 1.f/(red[0]+red[1]+red[2]+red[3]);
  for (int i=0;i<8;i++){
    int m = t + 256*i;
    P[n*2048 + m] = f2bf(arow[m]*inv);
  }
}

// ---------------------------------------------------------------------------
// K-mbits: msk u8 [n][m] -> transposed bitmaps mp2/mn2 u32 [n/32][m].
// grid (2048, 8), block 256.
// ---------------------------------------------------------------------------
__global__ void k_mbits(const u8* __restrict__ msk, u32* __restrict__ mp2, u32* __restrict__ mn2){
  const int m = blockIdx.x, nb = blockIdx.y*256;
  const int t = threadIdx.x, w = t>>6, lane = t&63;
  u8 v = msk[(size_t)(nb + t)*2048 + m];
  unsigned long long bp = __ballot(v == (u8)1);
  unsigned long long bn = __ballot(v == (u8)2);
  if (lane == 0){
    int wi = (nb + w*64) >> 5;
    mp2[(size_t)wi*2048 + m]     = (u32)bp;
    mp2[(size_t)(wi+1)*2048 + m] = (u32)(bp>>32);
    mn2[(size_t)wi*2048 + m]     = (u32)bn;
    mn2[(size_t)(wi+1)*2048 + m] = (u32)(bn>>32);
  }
}

// ---------------------------------------------------------------------------
// K2x: c1x[b,n,c] = sum_m P[n,m] * x[b,m,c]
// ---------------------------------------------------------------------------
__global__ void k_c1x(const u16* __restrict__ P, const float* __restrict__ x, float* __restrict__ c1x){
  const int t = threadIdx.x;
  const int r = t>>1, c = t&1;
  const int n = blockIdx.x*64 + r, b = blockIdx.y;
  const u16* pr = P + (size_t)n*2048;
  const float* xb = x + (size_t)b*2048*2 + c;
  float acc = 0.f;
  for (int m=0;m<2048;m+=4){
    acc += bf2f(pr[m+0])*xb[(m+0)*2];
    acc += bf2f(pr[m+1])*xb[(m+1)*2];
    acc += bf2f(pr[m+2])*xb[(m+2)*2];
    acc += bf2f(pr[m+3])*xb[(m+3)*2];
  }
  c1x[((size_t)b*2048 + n)*2 + c] = acc;
}

// ---------------------------------------------------------------------------
// K2: Y[b,n,d] = sum_m P[n,m] * Z[b,m,d], Z f32 [B,N,64]. 64x64 tile.
// ---------------------------------------------------------------------------
__global__ void k_conv(const u16* __restrict__ P, const float* __restrict__ Z, float* __restrict__ Y){
  __shared__ float Pt[16][68];
  __shared__ float Zt[16][68];
  const int t = threadIdx.x;
  const int tr = t>>4, tc = t&15;
  const int n0 = blockIdx.x*64, b = blockIdx.y;
  float acc[4][4] = {};
  for (int mt=0; mt<128; ++mt){
    int m0 = mt*16;
    {
      int r = t>>2, c4 = (t&3)*4;
      const u16* pp = P + (size_t)(n0+r)*2048 + m0 + c4;
      u32 p0 = *(const u32*)pp, p1v = *(const u32*)(pp+2);
      Pt[c4+0][r]=bf2f((u16)p0);  Pt[c4+1][r]=bf2f((u16)(p0>>16));
      Pt[c4+2][r]=bf2f((u16)p1v); Pt[c4+3][r]=bf2f((u16)(p1v>>16));
      int mm = t>>4, d0 = (t&15)*4;
      float4 zv = *(const float4*)&Z[((size_t)b*2048 + m0+mm)*64 + d0];
      Zt[mm][d0+0]=zv.x; Zt[mm][d0+1]=zv.y; Zt[mm][d0+2]=zv.z; Zt[mm][d0+3]=zv.w;
    }
    __syncthreads();
    #pragma unroll
    for (int mm=0; mm<16; ++mm){
      float4 a  = *(const float4*)&Pt[mm][tr*4];
      float4 bz = *(const float4*)&Zt[mm][tc*4];
      acc[0][0]+=a.x*bz.x; acc[0][1]+=a.x*bz.y; acc[0][2]+=a.x*bz.z; acc[0][3]+=a.x*bz.w;
      acc[1][0]+=a.y*bz.x; acc[1][1]+=a.y*bz.y; acc[1][2]+=a.y*bz.z; acc[1][3]+=a.y*bz.w;
      acc[2][0]+=a.z*bz.x; acc[2][1]+=a.z*bz.y; acc[2][2]+=a.z*bz.z; acc[2][3]+=a.z*bz.w;
      acc[3][0]+=a.w*bz.x; acc[3][1]+=a.w*bz.y; acc[3][2]+=a.w*bz.z; acc[3][3]+=a.w*bz.w;
    }
    __syncthreads();
  }
  #pragma unroll
  for (int i=0;i<4;i++){
    float4 v = make_float4(acc[i][0],acc[i][1],acc[i][2],acc[i][3]);
    *(float4*)&Y[((size_t)b*2048 + n0 + tr*4 + i)*64 + tc*4] = v;
  }
}

// ---------------------------------------------------------------------------
// K3: gate SAGC -> zs = z*state, rws = r. One block per node n.
// ---------------------------------------------------------------------------
__global__ void k_gate(const float* __restrict__ E, const float* __restrict__ gw, const float* __restrict__ gb,
                       const float* __restrict__ x, const float* __restrict__ state,
                       const float* __restrict__ c1x, const float* __restrict__ c1s,
                       float* __restrict__ zs, float* __restrict__ rws){
  __shared__ float Ew[16];
  __shared__ float bnv[128];
  __shared__ float Wn[2][66][64];
  __shared__ float xg4[4][2][66];
  const int t = threadIdx.x, n = blockIdx.x;
  if (t < 16) Ew[t] = E[n*16 + t];
  __syncthreads();
  if (t < 128){
    float a = 0.f;
    #pragma unroll
    for (int e=0;e<16;e++) a += Ew[e]*gb[e*128 + t];
    bnv[t] = a;
  }
  for (int half=0; half<2; ++half){
    for (int idx=t; idx<8448; idx+=256){
      int o = idx & 63, rest = idx>>6, i = rest % 66, k = rest / 66;
      float a = 0.f;
      #pragma unroll
      for (int e=0;e<16;e++) a += Ew[e]*gw[((e*2+k)*66 + i)*128 + half*64 + o];
      Wn[k][i][o] = a;
    }
    __syncthreads();
    for (int bb=0; bb<4; ++bb){
      for (int idx=t; idx<528; idx+=256){
        int bi = idx/132, rem = idx%132, k = rem/66, i = rem%66;
        int b = bb*4 + bi;
        float v;
        if (k==0) v = (i<2) ? x[((size_t)b*2048+n)*2 + i] : state[((size_t)b*2048+n)*64 + (i-2)];
        else      v = (i<2) ? c1x[((size_t)b*2048+n)*2 + i] : c1s[((size_t)b*2048+n)*64 + (i-2)];
        xg4[bi][k][i] = v;
      }
      __syncthreads();
      {
        int bi = t>>6, o = t&63, b = bb*4 + bi;
        float a = 0.f;
        #pragma unroll
        for (int k=0;k<2;k++)
          for (int i=0;i<66;i++) a += xg4[bi][k][i]*Wn[k][i][o];
        a += bnv[half*64 + o];
        float s = 1.f/(1.f + expf(-a));
        if (half==0) zs[((size_t)b*2048+n)*64 + o] = s*state[((size_t)b*2048+n)*64 + o];
        else         rws[((size_t)b*2048+n)*64 + o] = s;
      }
      __syncthreads();
    }
  }
}

// ---------------------------------------------------------------------------
// K3b: update SAGC -> hc -> h = r*state + (1-r)*hc.
// ---------------------------------------------------------------------------
__global__ void k_upd(const float* __restrict__ E, const float* __restrict__ uw, const float* __restrict__ ub,
                      const float* __restrict__ x, const float* __restrict__ state,
                      const float* __restrict__ zs, const float* __restrict__ c1x, const float* __restrict__ c2s,
                      const float* __restrict__ rws, float* __restrict__ h){
  __shared__ float Ew[16];
  __shared__ float bnu[64];
  __shared__ float Wn[2][66][64];
  __shared__ float xg4[4][2][66];
  const int t = threadIdx.x, n = blockIdx.x;
  if (t < 16) Ew[t] = E[n*16 + t];
  __syncthreads();
  if (t < 64){
    float a = 0.f;
    #pragma unroll
    for (int e=0;e<16;e++) a += Ew[e]*ub[e*64 + t];
    bnu[t] = a;
  }
  for (int idx=t; idx<8448; idx+=256){
    int o = idx & 63, rest = idx>>6, i = rest % 66, k = rest / 66;
    float a = 0.f;
    #pragma unroll
    for (int e=0;e<16;e++) a += Ew[e]*uw[((e*2+k)*66 + i)*64 + o];
    Wn[k][i][o] = a;
  }
  __syncthreads();
  for (int bb=0; bb<4; ++bb){
    for (int idx=t; idx<528; idx+=256){
      int bi = idx/132, rem = idx%132, k = rem/66, i = rem%66;
      int b = bb*4 + bi;
      float v;
      if (k==0) v = (i<2) ? x[((size_t)b*2048+n)*2 + i] : zs[((size_t)b*2048+n)*64 + (i-2)];
      else      v = (i<2) ? c1x[((size_t)b*2048+n)*2 + i] : c2s[((size_t)b*2048+n)*64 + (i-2)];
      xg4[bi][k][i] = v;
    }
    __syncthreads();
    {
      int bi = t>>6, o = t&63, b = bb*4 + bi;
      float a = 0.f;
      #pragma unroll
      for (int k=0;k<2;k++)
        for (int i=0;i<66;i++) a += xg4[bi][k][i]*Wn[k][i][o];
      float hc = tanhf(a + bnu[o]);
      float rv = rws[((size_t)b*2048+n)*64 + o];
      h[((size_t)b*2048+n)*64 + o] = rv*state[((size_t)b*2048+n)*64 + o] + (1.f - rv)*hc;
    }
    __syncthreads();
  }
}

// ---------------------------------------------------------------------------
// K5: fused degrees — R11: 16-wave (1024-thr) block, SAME 32-row tile.
// Theory: R10's MFMA-busy (124us) == phase-2 pipe floor; the other 240us is
// load-latency stall at 2 waves/SIMD (8-wave block, 1 block/CU across all
// rounds). 16 waves/block => guaranteed 4 waves/SIMD. Per-wave state halved
// to fit 128-VGPR cap at 4 waves/EU: acc 4xf32x16=64, single-buffer W staging
// 8xuint4=32, A-frags 8. Phase1: 8 ctgs/wave; phase2: 4 col-tiles/wave;
// phase4: m-halves split across wave pairs + LDS-scratch reduce (S dead).
// p0 rotation kept. fin=1 fuses final epilogue.
// ---------------------------------------------------------------------------
#define SROW8 2056

__global__ void __launch_bounds__(1024,4) k_deg(
    const u32* __restrict__ mbits, const u16* __restrict__ hb16,
    const u8* __restrict__ W8,
    const u8* __restrict__ ht8p, const u16* __restrict__ hfm,
    const float* __restrict__ hf32, const float* __restrict__ oc_in,
    float* __restrict__ outp, int fin){
  extern __shared__ u8 S[];
  __shared__ float redm[32][16];
  __shared__ float redsum[32][16];
  const int t = threadIdx.x;
  const int w = t >> 6, lane = t & 63, lc = lane & 15, q = lane >> 4;
  const int l32 = lane & 31, h32 = lane >> 5;
  const int id = blockIdx.x;
  const int b = id >> 6, n0 = (id & 63) * 32;
  const int p0 = (id >> 3) & 31;          // per-CU-within-XCD rotation offset
  const u32* mrow = mbits + (size_t)(n0 >> 5)*2048;
  const u16* hbb = hb16 + (size_t)b*2048*64;
  const u16* hfb = hfm + (size_t)b*131072;
  const u8* htb = ht8p + (size_t)b*131072;

  // ---- phase 1: S[r][m] = fp8( (bit ? h_n.h_m : 0) / 8 ); wave owns 8 ctgs ----
  {
    const int c0 = p0 & 7;
    bf16x8 A[2][2];
    #pragma unroll
    for (int rt=0; rt<2; ++rt)
      #pragma unroll
      for (int ks=0; ks<2; ++ks)
        A[rt][ks] = *(const bf16x8*)&hbb[(size_t)(n0 + rt*16 + lc)*64 + ks*32 + q*8];
    int ctg0 = w*8 + c0;
    bf16x8 B0c = *(const bf16x8*)(hfb + (size_t)ctg0*512 + lane*8);
    bf16x8 B1c = *(const bf16x8*)(hfb + 65536 + (size_t)ctg0*512 + lane*8);
    u32 mbc = mrow[ctg0*16 + lc];
    #pragma unroll 1
    for (int ct=0; ct<8; ++ct){
      const int ctg  = w*8 + ((ct + c0) & 7);
      const int ctgn = w*8 + ((ct + 1 + c0) & 7);
      bf16x8 B0n = *(const bf16x8*)(hfb + (size_t)ctgn*512 + lane*8);
      bf16x8 B1n = *(const bf16x8*)(hfb + 65536 + (size_t)ctgn*512 + lane*8);
      u32 mbn = mrow[ctgn*16 + lc];
      const int mcol = ctg*16 + lc;
      f32x4 a0 = {0.f,0.f,0.f,0.f}, a1 = {0.f,0.f,0.f,0.f};
      a0 = mfma_bf16(A[0][0], B0c, a0);
      a1 = mfma_bf16(A[1][0], B0c, a1);
      a0 = mfma_bf16(A[0][1], B1c, a0);
      a1 = mfma_bf16(A[1][1], B1c, a1);
      #pragma unroll
      for (int i=0;i<4;i++){
        int r0 = q*4 + i, r1 = 16 + q*4 + i;
        float v0 = ((mbc >> r0) & 1u) ? a0[i]*0.125f : 0.f;
        float v1 = ((mbc >> r1) & 1u) ? a1[i]*0.125f : 0.f;
        S[r0*SROW8 + mcol] = f2fp8(v0);
        S[r1*SROW8 + mcol] = f2fp8(v1);
      }
      B0c = B0n; B1c = B1n; mbc = mbn;
    }
  }
  __syncthreads();

  // ---- phase 2: logits = S @ W via 32x32x16 fp8; wave owns k-cols
  // [w*128, w*128+128) = col-tiles kt in [w*4, w*4+4). Single-buffer staging;
  // latency covered by 4 waves/SIMD TLP. ----
  f32x16 acc[4];
  #pragma unroll
  for (int tt=0;tt<4;++tt) acc[tt] = (f32x16)(0.f);
  {
    // A-frag addr: row = lane&31, m = pt*64 + s*16 + (lane>>5)*8
    const u8* abase = S + (size_t)l32*SROW8 + h32*8;
    // B blocks: ((pt*64 + kt)*2 + mcp)*1024; wave kt base = w*4.
    const u8* wbase = W8 + (size_t)(w*4)*2048 + lane*16;
    #pragma unroll 1
    for (int pti=0; pti<32; ++pti){
      const int pt = (pti + p0) & 31;
      const u8* wcur = wbase + (size_t)pt*131072;
      uint4 bv[8];
      #pragma unroll
      for (int i=0; i<8; ++i) bv[i] = *(const uint4*)(wcur + i*1024);
      long a[4];
      #pragma unroll
      for (int s=0; s<4; ++s) a[s] = *(const long*)(abase + pt*64 + s*16);
      #pragma unroll
      for (int s=0; s<4; ++s){
        #pragma unroll
        for (int k4=0; k4<4; ++k4){
          long bb = (s & 1) ? hi64(bv[k4*2 + (s>>1)]) : lo64(bv[k4*2 + (s>>1)]);
          acc[k4] = mfma_fp8_32(a[s], bb, acc[k4]);
        }
      }
    }
  }

  // ---- phase 3: row softmax over k (true logits = 0.5*acc) ----
  // C layout 32x32: col = lane&31, row = (g&3) + 8*(g>>2) + 4*(lane>>5)
  float gmax[16], gsc[16];
  #pragma unroll
  for (int g=0; g<16; ++g){
    float mx = acc[0][g];
    #pragma unroll
    for (int tt=1; tt<4; ++tt) mx = fmaxf(mx, acc[tt][g]);
    mx = fmaxf(mx, __shfl_xor(mx, 1));
    mx = fmaxf(mx, __shfl_xor(mx, 2));
    mx = fmaxf(mx, __shfl_xor(mx, 4));
    mx = fmaxf(mx, __shfl_xor(mx, 8));
    mx = fmaxf(mx, __shfl_xor(mx, 16));
    if (l32 == 0) redm[(g&3) + 8*(g>>2) + 4*h32][w] = mx;
  }
  __syncthreads();
  #pragma unroll
  for (int g=0; g<16; ++g){
    const int row = (g&3) + 8*(g>>2) + 4*h32;
    float4 u0 = *(const float4*)&redm[row][0];
    float4 u1 = *(const float4*)&redm[row][4];
    float4 u2 = *(const float4*)&redm[row][8];
    float4 u3 = *(const float4*)&redm[row][12];
    float m01 = fmaxf(fmaxf(fmaxf(u0.x,u0.y),fmaxf(u0.z,u0.w)),
                      fmaxf(fmaxf(u1.x,u1.y),fmaxf(u1.z,u1.w)));
    float m23 = fmaxf(fmaxf(fmaxf(u2.x,u2.y),fmaxf(u2.z,u2.w)),
                      fmaxf(fmaxf(u3.x,u3.y),fmaxf(u3.z,u3.w)));
    gmax[g] = fmaxf(m01, m23);
  }
  #pragma unroll
  for (int g=0; g<16; ++g){
    float s = 0.f;
    #pragma unroll
    for (int tt=0; tt<4; ++tt){
      float e = __expf(0.5f*(acc[tt][g] - gmax[g]));
      acc[tt][g] = e;
      s += e;
    }
    s += __shfl_xor(s, 1);
    s += __shfl_xor(s, 2);
    s += __shfl_xor(s, 4);
    s += __shfl_xor(s, 8);
    s += __shfl_xor(s, 16);
    if (l32 == 0) redsum[(g&3) + 8*(g>>2) + 4*h32][w] = s;
  }
  __syncthreads();
  #pragma unroll
  for (int g=0; g<16; ++g){
    const int row = (g&3) + 8*(g>>2) + 4*h32;
    float4 u0 = *(const float4*)&redsum[row][0];
    float4 u1 = *(const float4*)&redsum[row][4];
    float4 u2 = *(const float4*)&redsum[row][8];
    float4 u3 = *(const float4*)&redsum[row][12];
    float s = (u0.x+u0.y+u0.z+u0.w) + (u1.x+u1.y+u1.z+u1.w)
            + (u2.x+u2.y+u2.z+u2.w) + (u3.x+u3.y+u3.z+u3.w);
    gsc[g] = 256.f/s;
  }
  #pragma unroll
  for (int tt=0; tt<4; ++tt){
    const int col = (w*4 + tt)*32 + l32;
    #pragma unroll
    for (int g=0; g<16; ++g){
      const int row = (g&3) + 8*(g>>2) + 4*h32;
      S[row*SROW8 + col] = f2fp8(acc[tt][g]*gsc[g]);
    }
  }
  __syncthreads();

  // ---- phase 4: out = (deg*256) @ h / 256; 16 waves = 8 (rt,dt) x 2 m-halves;
  // partial reduce through S scratch (dead after A-reads). fin fuses final. ----
  {
    const int rt4 = w & 1, dt = (w >> 1) & 3, mh = w >> 3;
    f32x4 oe = {0.f,0.f,0.f,0.f}, oo = {0.f,0.f,0.f,0.f};
    const u8* abase = S + (size_t)(rt4*16 + lc)*SROW8 + q*8;
    const u8* bbase = htb + (size_t)dt*1024 + lane*16;
    const int pq = p0 & 15;
    uint4 bcur = *(const uint4*)(bbase + (size_t)(mh*16 + pq)*4096);
    #pragma unroll 1
    for (int pti=0; pti<16; ++pti){
      const int pt  = mh*16 + ((pti + pq) & 15);
      const int ptn = mh*16 + ((pti + 1 + pq) & 15);
      uint4 bnxt = *(const uint4*)(bbase + (size_t)ptn*4096);
      long ae = *(const long*)(abase + pt*64);
      long ao = *(const long*)(abase + pt*64 + 32);
      oe = mfma_fp8(ae, lo64(bcur), oe);
      oo = mfma_fp8(ao, hi64(bcur), oo);
      bcur = bnxt;
    }
    f32x4 o;
    #pragma unroll
    for (int i=0;i<4;i++) o[i] = oe[i] + oo[i];
    __syncthreads();                      // all S reads done
    if (mh == 1) *(f32x4*)(S + ((size_t)(w & 7)*64 + lane)*16) = o;
    __syncthreads();
    if (mh == 0){
      f32x4 p = *(const f32x4*)(S + ((size_t)w*64 + lane)*16);
      float* op = outp + (size_t)b*2048*64;
      const float* hp = hf32 + (size_t)b*2048*64;
      const float* cp = oc_in + (size_t)b*2048*64;
      #pragma unroll
      for (int i=0;i<4;i++){
        size_t idx = (size_t)(n0 + rt4*16 + q*4 + i)*64 + dt*16 + lc;
        float v = (o[i] + p[i])*(1.f/256.f);
        if (fin) v = 0.8f*hp[idx] - 0.1f*cp[idx] + 0.1f*v;
        op[idx] = v;
      }
    }
  }
}

// ---------------------------------------------------------------------------
extern "C" void kernel_launch(void* const* d_in, const int* in_sizes, int n_in,
                              void* d_out, int out_size, void* d_ws, size_t ws_size,
                              hipStream_t stream) {
  const float* x     = (const float*)d_in[0];
  const float* state = (const float*)d_in[1];
  const float* E     = (const float*)d_in[2];
  const float* Wc    = (const float*)d_in[3];
  const float* Wd    = (const float*)d_in[4];
  const float* gw    = (const float*)d_in[5];
  const float* gb    = (const float*)d_in[6];
  const float* uw    = (const float*)d_in[7];
  const float* ub    = (const float*)d_in[8];

  // workspace layout (bytes). Total 73,662,464 B = 70.2 MB.
  char* base = (char*)d_ws;
  u16*   P    = (u16*)(base + 0);           //  8,388,608  (dead after 2nd k_conv)
  u32*   mp2  = (u32*)(base + 0);           //    524,288  (aliases P; written after P dead)
  u32*   mn2  = (u32*)(base + 524288);      //    524,288  (aliases P)
  u8*    msk  = (u8*) (base + 8388608);     //  4,194,304
  u8*    Wc8  = (u8*) (base + 12582912);    //  4,194,304
  u8*    Wd8  = (u8*) (base + 16777216);    //  4,194,304
  u16*   hb16 = (u16*)(base + 20971520);    //  4,194,304
  u8*    ht8p = (u8*) (base + 25165824);    //  2,097,152
  u16*   hfm  = (u16*)(base + 27262976);    //  4,194,304
  float* c1x  = (float*)(base + 31457280);  //    262,144
  float* c1s  = (float*)(base + 31719424);  //  8,388,608
  float* zs   = (float*)(base + 40108032);  //  8,388,608
  float* rws  = (float*)(base + 48496640);  //  8,388,608
  float* c2s  = (float*)(base + 56885248);  //  8,388,608
  float* h    = (float*)(base + 65273856);  //  8,388,608
  float* oc   = c1s;                        // dead after k_gate
  float* od   = c2s;                        // dead after k_upd (unused placeholder)

  k_w8<<<dim3(32,32,2), 256, 0, stream>>>(Wc, Wd, Wc8, Wd8);
  k_P<<<2048, 256, 0, stream>>>(E, P, msk);
  k_c1x<<<dim3(32,16), 128, 0, stream>>>(P, x, c1x);
  k_conv<<<dim3(32,16), 256, 0, stream>>>(P, state, c1s);
  k_gate<<<2048, 256, 0, stream>>>(E, gw, gb, x, state, c1x, c1s, zs, rws);
  k_conv<<<dim3(32,16), 256, 0, stream>>>(P, zs, c2s);
  k_upd<<<2048, 256, 0, stream>>>(E, uw, ub, x, state, zs, c1x, c2s, rws, h);
  k_hcvt<<<dim3(32,16), 256, 0, stream>>>(h, hb16, ht8p, hfm);
  k_mbits<<<dim3(2048,8), 256, 0, stream>>>(msk, mp2, mn2);   // P dead by now

  const int deg_lds = 32*SROW8;   // 65,792 B dynamic (+4 KB static red arrays)
  hipFuncSetAttribute((const void*)k_deg, hipFuncAttributeMaxDynamicSharedMemorySize, deg_lds);
  // dispatch 1: connect mask — only Wc8 hot in every XCD L2
  k_deg<<<1024, 1024, deg_lds, stream>>>(mp2, hb16, Wc8, ht8p, hfm, h, h, oc, 0);
  // dispatch 2: disconnect mask — only Wd8 hot; fused final epilogue -> d_out
  k_deg<<<1024, 1024, deg_lds, stream>>>(mn2, hb16, Wd8, ht8p, hfm, h, oc, (float*)d_out, 1);
}

// Round 5
// 1256.851 us; speedup vs baseline: 1.5031x; 1.5031x over previous
//
#include <hip/hip_runtime.h>
#include <hip/hip_bf16.h>

typedef unsigned short u16;
typedef unsigned int   u32;
typedef unsigned char  u8;

typedef __attribute__((ext_vector_type(8))) short bf16x8;
typedef __attribute__((ext_vector_type(4))) float f32x4;
typedef __attribute__((ext_vector_type(16))) float f32x16;

static __device__ __forceinline__ float bf2f(u16 u){ return __uint_as_float(((u32)u)<<16); }
static __device__ __forceinline__ u16 f2bf(float f){
  u32 u = __float_as_uint(f);
  u32 r = (u + 0x7fff + ((u>>16)&1)) >> 16;   // RNE; inputs finite
  return (u16)r;
}

// fp8 e4m3 (OCP) helpers — HW cvt, saturating via pre-clamp
static __device__ __forceinline__ u8 f2fp8(float v){
  v = fminf(440.f, fmaxf(-440.f, v));
  return (u8)(__builtin_amdgcn_cvt_pk_fp8_f32(v, 0.f, 0, false) & 0xff);
}
static __device__ __forceinline__ u32 pk4_fp8(float a, float b, float c, float d){
  int w = __builtin_amdgcn_cvt_pk_fp8_f32(a, b, 0, false);
  w = __builtin_amdgcn_cvt_pk_fp8_f32(c, d, w, true);
  return (u32)w;
}

static __device__ __forceinline__ f32x4 mfma_bf16(bf16x8 a, bf16x8 b, f32x4 c){
  return __builtin_amdgcn_mfma_f32_16x16x32_bf16(a, b, c, 0, 0, 0);
}
static __device__ __forceinline__ f32x16 mfma_fp8_32(long a, long b, f32x16 c){
  return __builtin_amdgcn_mfma_f32_32x32x16_fp8_fp8(a, b, c, 0, 0, 0);
}
static __device__ __forceinline__ long lo64(uint4 v){ return (long)(((unsigned long long)v.y<<32) | v.x); }
static __device__ __forceinline__ long hi64(uint4 v){ return (long)(((unsigned long long)v.w<<32) | v.z); }
static __device__ __forceinline__ long mklong(u32 lo, u32 hi){ return (long)(((unsigned long long)hi<<32) | lo); }

// ---------------------------------------------------------------------------
// K-w8: W f32 [m][k] -> fp8 packed, 1KB block per (pt=m/64, kt=k/32, mcp):
//   byte at lane*16 + sel*8 + j = W[pt*64 + (mcp*2+sel)*16 + (lane>>5)*8 + j][kt*32 + (lane&31)]
// Serves BOTH as 32x32x16 B-frag (m x k) and as A-frag of W^T (k x m).
// grid (32,32,2), block 256.
// ---------------------------------------------------------------------------
__global__ void k_w8(const float* __restrict__ Wc, const float* __restrict__ Wd,
                     u8* __restrict__ Wc8, u8* __restrict__ Wd8){
  __shared__ float tile[64][65];
  const float* src = blockIdx.z ? Wd : Wc;
  u8* dst = blockIdx.z ? Wd8 : Wc8;
  const int m0 = blockIdx.x*64, k0 = blockIdx.y*64;
  const int t = threadIdx.x, r = t & 63, cc = t >> 6;
  #pragma unroll
  for (int j=0;j<4;j++){
    float4 v = *(const float4*)&src[(size_t)(m0+r)*2048 + k0 + cc*16 + j*4];
    tile[r][cc*16+j*4+0]=v.x; tile[r][cc*16+j*4+1]=v.y;
    tile[r][cc*16+j*4+2]=v.z; tile[r][cc*16+j*4+3]=v.w;
  }
  __syncthreads();
  const int lane = t & 63, sub = t >> 6;     // sub 0..3
  const int kth = sub & 1, mcp = sub >> 1;
  const int kl = kth*32 + (lane & 31);       // k within 64-tile
  const int ml = mcp*32 + (lane >> 5)*8;     // m base within 64-tile
  u32 b0 = pk4_fp8(16.f*tile[ml+ 0][kl], 16.f*tile[ml+ 1][kl], 16.f*tile[ml+ 2][kl], 16.f*tile[ml+ 3][kl]);
  u32 b1 = pk4_fp8(16.f*tile[ml+ 4][kl], 16.f*tile[ml+ 5][kl], 16.f*tile[ml+ 6][kl], 16.f*tile[ml+ 7][kl]);
  u32 b2 = pk4_fp8(16.f*tile[ml+16][kl], 16.f*tile[ml+17][kl], 16.f*tile[ml+18][kl], 16.f*tile[ml+19][kl]);
  u32 b3 = pk4_fp8(16.f*tile[ml+20][kl], 16.f*tile[ml+21][kl], 16.f*tile[ml+22][kl], 16.f*tile[ml+23][kl]);
  const int pt = m0 >> 6, kt = (k0 >> 5) + kth;
  u8* dbase = dst + (size_t)((pt*64 + kt)*2 + mcp)*1024 + lane*16;
  *(uint4*)dbase = make_uint4(b0, b1, b2, b3);
}

// ---------------------------------------------------------------------------
// K-hcvt: h f32 [b][m][64] -> hb16 (bf16 row-major), hfm (bf16 frag-major B for
// phase 1), ht8p (fp8 32x32x16-B frags: addr (k16*2 + dt)*512 + lane*8 + j ->
// h[k16*16 + (lane>>5)*8 + j][dt*32 + (lane&31)]). grid (32,16), block 256.
// ---------------------------------------------------------------------------
__global__ void k_hcvt(const float* __restrict__ h, u16* __restrict__ hb16,
                       u8* __restrict__ ht8p, u16* __restrict__ hfm){
  __shared__ float tile[64][65];
  const int k0 = blockIdx.x*64, b = blockIdx.y;
  const int t = threadIdx.x, r = t & 63, cc = t >> 6;
  const float* src = h + ((size_t)b*2048 + k0)*64;
  u32 hw[8];
  #pragma unroll
  for (int j=0;j<4;j++){
    float4 v = *(const float4*)&src[(size_t)r*64 + cc*16 + j*4];
    tile[r][cc*16+j*4+0]=v.x; tile[r][cc*16+j*4+1]=v.y;
    tile[r][cc*16+j*4+2]=v.z; tile[r][cc*16+j*4+3]=v.w;
    hw[2*j]   = (u32)f2bf(v.x) | ((u32)f2bf(v.y)<<16);
    hw[2*j+1] = (u32)f2bf(v.z) | ((u32)f2bf(v.w)<<16);
  }
  u16* hp = hb16 + (((size_t)b*2048 + k0 + r)*64 + cc*16);
  *(uint4*)hp     = make_uint4(hw[0],hw[1],hw[2],hw[3]);
  *(uint4*)(hp+8) = make_uint4(hw[4],hw[5],hw[6],hw[7]);
  __syncthreads();
  {
    // ht8p: 32x32x16 B-frag layout for out-MFMA (k x d)
    const int lane = t & 63, sub = cc;          // sub = local k16 index 0..3
    const int k16 = (k0 >> 4) + sub;
    const int lr = sub*16 + ((lane >> 5) << 3); // local row in tile
    const int d0 = lane & 31;
    #pragma unroll
    for (int dt=0; dt<2; ++dt){
      const int d = dt*32 + d0;
      u32 w0 = pk4_fp8(tile[lr+0][d], tile[lr+1][d], tile[lr+2][d], tile[lr+3][d]);
      u32 w1 = pk4_fp8(tile[lr+4][d], tile[lr+5][d], tile[lr+6][d], tile[lr+7][d]);
      *(uint2*)(ht8p + (size_t)b*131072 + (size_t)(k16*2 + dt)*512 + lane*8) = make_uint2(w0, w1);
    }
  }
  {
    const int col = k0 + r, ks = cc >> 1, q0 = (cc & 1)*2;
    const int ctg = col >> 4, lcv = col & 15;
    u16* fbase = hfm + (size_t)b*131072 + (size_t)ks*65536 + ((size_t)ctg*64)*8;
    #pragma unroll
    for (int qq=0; qq<2; ++qq){
      int q = q0 + qq;
      u32 p0 = (u32)f2bf(tile[r][ks*32+q*8+0]) | ((u32)f2bf(tile[r][ks*32+q*8+1])<<16);
      u32 p1 = (u32)f2bf(tile[r][ks*32+q*8+2]) | ((u32)f2bf(tile[r][ks*32+q*8+3])<<16);
      u32 p2 = (u32)f2bf(tile[r][ks*32+q*8+4]) | ((u32)f2bf(tile[r][ks*32+q*8+5])<<16);
      u32 p3 = (u32)f2bf(tile[r][ks*32+q*8+6]) | ((u32)f2bf(tile[r][ks*32+q*8+7])<<16);
      *(uint4*)(fbase + (size_t)(q*16 + lcv)*8) = make_uint4(p0,p1,p2,p3);
    }
  }
}

// ---------------------------------------------------------------------------
// K1: row n of A = E E^T. sign-mask (1 pos, 2 neg) + P=softmax(relu) bf16.
// ---------------------------------------------------------------------------
__global__ void k_P(const float* __restrict__ E, u16* __restrict__ P, u8* __restrict__ msk){
  __shared__ float Ew[16];
  __shared__ float arow[2048];
  __shared__ float red[4];
  const int t = threadIdx.x, n = blockIdx.x;
  if (t < 16) Ew[t] = E[n*16 + t];
  __syncthreads();
  float lmax = 0.f;
  for (int i=0;i<8;i++){
    int m = t + 256*i;
    const float* ep = E + m*16;
    float dot = 0.f;
    #pragma unroll
    for (int d=0; d<16; ++d) dot += Ew[d]*ep[d];
    msk[n*2048 + m] = dot > 0.f ? (u8)1 : (dot < 0.f ? (u8)2 : (u8)0);
    float ar = fmaxf(dot, 0.f);
    arow[m] = ar;
    lmax = fmaxf(lmax, ar);
  }
  for (int o=1;o<64;o<<=1) lmax = fmaxf(lmax, __shfl_xor(lmax, o));
  if ((t&63)==0) red[t>>6] = lmax;
  __syncthreads();
  float gmax = fmaxf(fmaxf(red[0],red[1]), fmaxf(red[2],red[3]));
  __syncthreads();
  float lsum = 0.f;
  for (int i=0;i<8;i++){
    int m = t + 256*i;
    float e = expf(arow[m] - gmax);
    arow[m] = e;
    lsum += e;
  }
  for (int o=1;o<64;o<<=1) lsum += __shfl_xor(lsum, o);
  if ((t&63)==0) red[t>>6] = lsum;
  __syncthreads();
  float inv = 1.f/(red[0]+red[1]+red[2]+red[3]);
  for (int i=0;i<8;i++){
    int m = t + 256*i;
    P[n*2048 + m] = f2bf(arow[m]*inv);
  }
}

// ---------------------------------------------------------------------------
// K-mbits: msk u8 [n][m] -> transposed bitmaps mp2/mn2 u32 [n/32][m].
// grid (2048, 8), block 256.
// ---------------------------------------------------------------------------
__global__ void k_mbits(const u8* __restrict__ msk, u32* __restrict__ mp2, u32* __restrict__ mn2){
  const int m = blockIdx.x, nb = blockIdx.y*256;
  const int t = threadIdx.x, w = t>>6, lane = t&63;
  u8 v = msk[(size_t)(nb + t)*2048 + m];
  unsigned long long bp = __ballot(v == (u8)1);
  unsigned long long bn = __ballot(v == (u8)2);
  if (lane == 0){
    int wi = (nb + w*64) >> 5;
    mp2[(size_t)wi*2048 + m]     = (u32)bp;
    mp2[(size_t)(wi+1)*2048 + m] = (u32)(bp>>32);
    mn2[(size_t)wi*2048 + m]     = (u32)bn;
    mn2[(size_t)(wi+1)*2048 + m] = (u32)(bn>>32);
  }
}

// ---------------------------------------------------------------------------
// K2x: c1x[b,n,c] = sum_m P[n,m] * x[b,m,c]
// ---------------------------------------------------------------------------
__global__ void k_c1x(const u16* __restrict__ P, const float* __restrict__ x, float* __restrict__ c1x){
  const int t = threadIdx.x;
  const int r = t>>1, c = t&1;
  const int n = blockIdx.x*64 + r, b = blockIdx.y;
  const u16* pr = P + (size_t)n*2048;
  const float* xb = x + (size_t)b*2048*2 + c;
  float acc = 0.f;
  for (int m=0;m<2048;m+=4){
    acc += bf2f(pr[m+0])*xb[(m+0)*2];
    acc += bf2f(pr[m+1])*xb[(m+1)*2];
    acc += bf2f(pr[m+2])*xb[(m+2)*2];
    acc += bf2f(pr[m+3])*xb[(m+3)*2];
  }
  c1x[((size_t)b*2048 + n)*2 + c] = acc;
}

// ---------------------------------------------------------------------------
// K2: Y[b,n,d] = sum_m P[n,m] * Z[b,m,d], Z f32 [B,N,64]. 64x64 tile.
// ---------------------------------------------------------------------------
__global__ void k_conv(const u16* __restrict__ P, const float* __restrict__ Z, float* __restrict__ Y){
  __shared__ float Pt[16][68];
  __shared__ float Zt[16][68];
  const int t = threadIdx.x;
  const int tr = t>>4, tc = t&15;
  const int n0 = blockIdx.x*64, b = blockIdx.y;
  float acc[4][4] = {};
  for (int mt=0; mt<128; ++mt){
    int m0 = mt*16;
    {
      int r = t>>2, c4 = (t&3)*4;
      const u16* pp = P + (size_t)(n0+r)*2048 + m0 + c4;
      u32 p0 = *(const u32*)pp, p1v = *(const u32*)(pp+2);
      Pt[c4+0][r]=bf2f((u16)p0);  Pt[c4+1][r]=bf2f((u16)(p0>>16));
      Pt[c4+2][r]=bf2f((u16)p1v); Pt[c4+3][r]=bf2f((u16)(p1v>>16));
      int mm = t>>4, d0 = (t&15)*4;
      float4 zv = *(const float4*)&Z[((size_t)b*2048 + m0+mm)*64 + d0];
      Zt[mm][d0+0]=zv.x; Zt[mm][d0+1]=zv.y; Zt[mm][d0+2]=zv.z; Zt[mm][d0+3]=zv.w;
    }
    __syncthreads();
    #pragma unroll
    for (int mm=0; mm<16; ++mm){
      float4 a  = *(const float4*)&Pt[mm][tr*4];
      float4 bz = *(const float4*)&Zt[mm][tc*4];
      acc[0][0]+=a.x*bz.x; acc[0][1]+=a.x*bz.y; acc[0][2]+=a.x*bz.z; acc[0][3]+=a.x*bz.w;
      acc[1][0]+=a.y*bz.x; acc[1][1]+=a.y*bz.y; acc[1][2]+=a.y*bz.z; acc[1][3]+=a.y*bz.w;
      acc[2][0]+=a.z*bz.x; acc[2][1]+=a.z*bz.y; acc[2][2]+=a.z*bz.z; acc[2][3]+=a.z*bz.w;
      acc[3][0]+=a.w*bz.x; acc[3][1]+=a.w*bz.y; acc[3][2]+=a.w*bz.z; acc[3][3]+=a.w*bz.w;
    }
    __syncthreads();
  }
  #pragma unroll
  for (int i=0;i<4;i++){
    float4 v = make_float4(acc[i][0],acc[i][1],acc[i][2],acc[i][3]);
    *(float4*)&Y[((size_t)b*2048 + n0 + tr*4 + i)*64 + tc*4] = v;
  }
}

// ---------------------------------------------------------------------------
// K3: gate SAGC -> zs = z*state, rws = r. One block per node n.
// ---------------------------------------------------------------------------
__global__ void k_gate(const float* __restrict__ E, const float* __restrict__ gw, const float* __restrict__ gb,
                       const float* __restrict__ x, const float* __restrict__ state,
                       const float* __restrict__ c1x, const float* __restrict__ c1s,
                       float* __restrict__ zs, float* __restrict__ rws){
  __shared__ float Ew[16];
  __shared__ float bnv[128];
  __shared__ float Wn[2][66][64];
  __shared__ float xg4[4][2][66];
  const int t = threadIdx.x, n = blockIdx.x;
  if (t < 16) Ew[t] = E[n*16 + t];
  __syncthreads();
  if (t < 128){
    float a = 0.f;
    #pragma unroll
    for (int e=0;e<16;e++) a += Ew[e]*gb[e*128 + t];
    bnv[t] = a;
  }
  for (int half=0; half<2; ++half){
    for (int idx=t; idx<8448; idx+=256){
      int o = idx & 63, rest = idx>>6, i = rest % 66, k = rest / 66;
      float a = 0.f;
      #pragma unroll
      for (int e=0;e<16;e++) a += Ew[e]*gw[((e*2+k)*66 + i)*128 + half*64 + o];
      Wn[k][i][o] = a;
    }
    __syncthreads();
    for (int bb=0; bb<4; ++bb){
      for (int idx=t; idx<528; idx+=256){
        int bi = idx/132, rem = idx%132, k = rem/66, i = rem%66;
        int b = bb*4 + bi;
        float v;
        if (k==0) v = (i<2) ? x[((size_t)b*2048+n)*2 + i] : state[((size_t)b*2048+n)*64 + (i-2)];
        else      v = (i<2) ? c1x[((size_t)b*2048+n)*2 + i] : c1s[((size_t)b*2048+n)*64 + (i-2)];
        xg4[bi][k][i] = v;
      }
      __syncthreads();
      {
        int bi = t>>6, o = t&63, b = bb*4 + bi;
        float a = 0.f;
        #pragma unroll
        for (int k=0;k<2;k++)
          for (int i=0;i<66;i++) a += xg4[bi][k][i]*Wn[k][i][o];
        a += bnv[half*64 + o];
        float s = 1.f/(1.f + expf(-a));
        if (half==0) zs[((size_t)b*2048+n)*64 + o] = s*state[((size_t)b*2048+n)*64 + o];
        else         rws[((size_t)b*2048+n)*64 + o] = s;
      }
      __syncthreads();
    }
  }
}

// ---------------------------------------------------------------------------
// K3b: update SAGC -> hc -> h = r*state + (1-r)*hc.
// ---------------------------------------------------------------------------
__global__ void k_upd(const float* __restrict__ E, const float* __restrict__ uw, const float* __restrict__ ub,
                      const float* __restrict__ x, const float* __restrict__ state,
                      const float* __restrict__ zs, const float* __restrict__ c1x, const float* __restrict__ c2s,
                      const float* __restrict__ rws, float* __restrict__ h){
  __shared__ float Ew[16];
  __shared__ float bnu[64];
  __shared__ float Wn[2][66][64];
  __shared__ float xg4[4][2][66];
  const int t = threadIdx.x, n = blockIdx.x;
  if (t < 16) Ew[t] = E[n*16 + t];
  __syncthreads();
  if (t < 64){
    float a = 0.f;
    #pragma unroll
    for (int e=0;e<16;e++) a += Ew[e]*ub[e*64 + t];
    bnu[t] = a;
  }
  for (int idx=t; idx<8448; idx+=256){
    int o = idx & 63, rest = idx>>6, i = rest % 66, k = rest / 66;
    float a = 0.f;
    #pragma unroll
    for (int e=0;e<16;e++) a += Ew[e]*uw[((e*2+k)*66 + i)*64 + o];
    Wn[k][i][o] = a;
  }
  __syncthreads();
  for (int bb=0; bb<4; ++bb){
    for (int idx=t; idx<528; idx+=256){
      int bi = idx/132, rem = idx%132, k = rem/66, i = rem%66;
      int b = bb*4 + bi;
      float v;
      if (k==0) v = (i<2) ? x[((size_t)b*2048+n)*2 + i] : zs[((size_t)b*2048+n)*64 + (i-2)];
      else      v = (i<2) ? c1x[((size_t)b*2048+n)*2 + i] : c2s[((size_t)b*2048+n)*64 + (i-2)];
      xg4[bi][k][i] = v;
    }
    __syncthreads();
    {
      int bi = t>>6, o = t&63, b = bb*4 + bi;
      float a = 0.f;
      #pragma unroll
      for (int k=0;k<2;k++)
        for (int i=0;i<66;i++) a += xg4[bi][k][i]*Wn[k][i][o];
      float hc = tanhf(a + bnu[o]);
      float rv = rws[((size_t)b*2048+n)*64 + o];
      h[((size_t)b*2048+n)*64 + o] = rv*state[((size_t)b*2048+n)*64 + o] + (1.f - rv)*hc;
    }
    __syncthreads();
  }
}

// ---------------------------------------------------------------------------
// K5: fused degrees — R12: flash-style fusion of phases 2+3+4.
// 64-row blocks (512 blocks x 512 thr, 8 waves, S = 64x2056 fp8 = 131.6 KB).
// W L2 traffic HALVED (2.15 GB/dispatch, ~63us of L2 < 126us MFMA floor).
// Swapped logit GEMM: logitT[k,n] = W^T @ S^T — W8 blocks are valid A-frags
// as-is; S reads unchanged. C-layout: col=n(lane&31), row=k((g&3)+8(g>>2)+4h32).
// Wave = one n-half (32 rows) x 512 k-cols, online softmax over 4 super-iters
// of 128 k; barrier-free until the final log-sum-exp merge through S (dead).
// P exp'd in-reg (256-scaled), packed to fp8 via pk4+shfl_xor(32), fed to
// out-MFMA (A=P, B=ht frags). Regs ~190 <= 256 cap (512,2). p0 rotation kept.
// ---------------------------------------------------------------------------
#define SROW8 2056

__global__ void __launch_bounds__(512,2) k_deg(
    const u32* __restrict__ mbits, const u16* __restrict__ hb16,
    const u8* __restrict__ W8,
    const u8* __restrict__ ht8p, const u16* __restrict__ hfm,
    const float* __restrict__ hf32, const float* __restrict__ oc_in,
    float* __restrict__ outp, int fin){
  extern __shared__ u8 S[];
  __shared__ float maxw[64][4];
  __shared__ float sumw[64][4];
  __shared__ float sgl_lds[64];
  const int t = threadIdx.x;
  const int w = t >> 6, lane = t & 63, lc = lane & 15, q = lane >> 4;
  const int l32 = lane & 31, h32 = lane >> 5;
  const int id = blockIdx.x;
  const int b = id >> 5, n0 = (id & 31) * 64;
  const int p0 = (id >> 3) & 31;          // per-CU-within-XCD rotation offset
  const u32* mrow0 = mbits + (size_t)(n0 >> 5)*2048;
  const u32* mrow1 = mrow0 + 2048;
  const u16* hbb = hb16 + (size_t)b*2048*64;
  const u16* hfb = hfm + (size_t)b*131072;
  const u8* htb = ht8p + (size_t)b*131072;

  // ---- phase 1: S[r][m] = fp8( (bit ? h_n.h_m : 0) / 8 ), 64 rows ----
  {
    const int c0 = p0 & 15;
    bf16x8 A[4][2];
    #pragma unroll
    for (int rt=0; rt<4; ++rt)
      #pragma unroll
      for (int ks=0; ks<2; ++ks)
        A[rt][ks] = *(const bf16x8*)&hbb[(size_t)(n0 + rt*16 + lc)*64 + ks*32 + q*8];
    int ctg0 = w*16 + c0;
    bf16x8 B0c = *(const bf16x8*)(hfb + (size_t)ctg0*512 + lane*8);
    bf16x8 B1c = *(const bf16x8*)(hfb + 65536 + (size_t)ctg0*512 + lane*8);
    u32 m0c = mrow0[ctg0*16 + lc], m1c = mrow1[ctg0*16 + lc];
    #pragma unroll 1
    for (int ct=0; ct<16; ++ct){
      const int ctg  = w*16 + ((ct + c0) & 15);
      const int ctgn = w*16 + ((ct + 1 + c0) & 15);
      bf16x8 B0n = *(const bf16x8*)(hfb + (size_t)ctgn*512 + lane*8);
      bf16x8 B1n = *(const bf16x8*)(hfb + 65536 + (size_t)ctgn*512 + lane*8);
      u32 m0n = mrow0[ctgn*16 + lc], m1n = mrow1[ctgn*16 + lc];
      const int mcol = ctg*16 + lc;
      f32x4 a[4];
      #pragma unroll
      for (int rt=0; rt<4; ++rt){
        a[rt] = (f32x4){0.f,0.f,0.f,0.f};
        a[rt] = mfma_bf16(A[rt][0], B0c, a[rt]);
        a[rt] = mfma_bf16(A[rt][1], B1c, a[rt]);
      }
      #pragma unroll
      for (int rt=0; rt<4; ++rt){
        const u32 mw = (rt < 2) ? m0c : m1c;
        #pragma unroll
        for (int i=0;i<4;i++){
          const int row = rt*16 + q*4 + i;
          float v = ((mw >> (row & 31)) & 1u) ? a[rt][i]*0.125f : 0.f;
          S[row*SROW8 + mcol] = f2fp8(v);
        }
      }
      B0c = B0n; B1c = B1n; m0c = m0n; m1c = m1n;
    }
  }
  __syncthreads();

  // ---- fused phases 2+3+4: online softmax + PV, barrier-free per wave ----
  // wave w: n-half nh = w>>2 (rows nh*32..+32), k-slice kq = w&3 (cols kq*512..+512)
  const int nh = w >> 2, kq = w & 3;
  const u8* sbase = S + (size_t)(nh*32 + l32)*SROW8 + h32*8;
  const u8* wl = W8 + lane*16;
  f32x16 o0 = (f32x16)(0.f), o1 = (f32x16)(0.f);
  float mrun = -1e30f, srun = 0.f;
  const float LN256 = 5.545177444479562f;
  #pragma unroll 1
  for (int si = 0; si < 4; ++si){
    const int ktb = kq*16 + si*4;
    f32x16 L[4];
    #pragma unroll
    for (int tt=0; tt<4; ++tt) L[tt] = (f32x16)(0.f);
    #pragma unroll 1
    for (int pti = 0; pti < 32; ++pti){
      const int pt = (pti + p0) & 31;
      long b0 = *(const long*)(sbase + pt*64 +  0);
      long b1 = *(const long*)(sbase + pt*64 + 16);
      long b2 = *(const long*)(sbase + pt*64 + 32);
      long b3 = *(const long*)(sbase + pt*64 + 48);
      uint4 wv[8];
      #pragma unroll
      for (int tt=0; tt<4; ++tt){
        wv[tt*2+0] = *(const uint4*)(wl + (size_t)((pt*64 + ktb+tt)*2 + 0)*1024);
        wv[tt*2+1] = *(const uint4*)(wl + (size_t)((pt*64 + ktb+tt)*2 + 1)*1024);
      }
      #pragma unroll
      for (int tt=0; tt<4; ++tt) L[tt] = mfma_fp8_32(lo64(wv[tt*2+0]), b0, L[tt]);
      #pragma unroll
      for (int tt=0; tt<4; ++tt) L[tt] = mfma_fp8_32(hi64(wv[tt*2+0]), b1, L[tt]);
      #pragma unroll
      for (int tt=0; tt<4; ++tt) L[tt] = mfma_fp8_32(lo64(wv[tt*2+1]), b2, L[tt]);
      #pragma unroll
      for (int tt=0; tt<4; ++tt) L[tt] = mfma_fp8_32(hi64(wv[tt*2+1]), b3, L[tt]);
    }
    // chunk max (logit units = 0.5*acc); n = l32 per lane
    float cmax = L[0][0];
    #pragma unroll
    for (int tt=0; tt<4; ++tt)
      #pragma unroll
      for (int g=0; g<16; ++g) cmax = fmaxf(cmax, L[tt][g]);
    cmax = fmaxf(cmax, __shfl_xor(cmax, 32));
    float mnew = fmaxf(mrun, 0.5f*cmax);
    float sc = __expf(mrun - mnew);
    srun *= sc;
    // rescale out (rows = n): pull per-row factor from lane rowl
    #pragma unroll
    for (int g=0; g<16; ++g){
      const int rowl = (g&3) + 8*(g>>2) + 4*h32;
      float fr = __shfl(sc, rowl);
      o0[g] *= fr; o1[g] *= fr;
    }
    float cs = 0.f;
    #pragma unroll
    for (int tt=0; tt<4; ++tt){
      float p[16];
      #pragma unroll
      for (int g=0; g<16; ++g){
        p[g] = __expf(0.5f*L[tt][g] - mnew + LN256);   // 256-scaled
        cs += p[g];
      }
      u32 qA = pk4_fp8(p[0],p[1],p[2],p[3]);
      u32 qB = pk4_fp8(p[4],p[5],p[6],p[7]);
      u32 qC = pk4_fp8(p[8],p[9],p[10],p[11]);
      u32 qD = pk4_fp8(p[12],p[13],p[14],p[15]);
      u32 xA = __shfl_xor(qA, 32), xB = __shfl_xor(qB, 32);
      u32 xC = __shfl_xor(qC, 32), xD = __shfl_xor(qD, 32);
      // A-frags of P (n x k): k-chunk0 = k 0..15 of tile, chunk1 = 16..31
      long pf0 = h32 ? mklong(xB, qB) : mklong(qA, xA);
      long pf1 = h32 ? mklong(xD, qD) : mklong(qC, xC);
      const int kt = ktb + tt;
      long h00 = *(const long*)(htb + (size_t)((kt*2+0)*2 + 0)*512 + lane*8);
      long h01 = *(const long*)(htb + (size_t)((kt*2+0)*2 + 1)*512 + lane*8);
      long h10 = *(const long*)(htb + (size_t)((kt*2+1)*2 + 0)*512 + lane*8);
      long h11 = *(const long*)(htb + (size_t)((kt*2+1)*2 + 1)*512 + lane*8);
      o0 = mfma_fp8_32(pf0, h00, o0);
      o1 = mfma_fp8_32(pf0, h01, o1);
      o0 = mfma_fp8_32(pf1, h10, o0);
      o1 = mfma_fp8_32(pf1, h11, o1);
    }
    cs += __shfl_xor(cs, 32);
    srun += cs;
    mrun = mnew;
  }

  // ---- merge: log-sum-exp combine of 4 k-slices per n-half ----
  if (lane < 32){
    maxw[nh*32 + lane][kq] = mrun;
    sumw[nh*32 + lane][kq] = srun;
  }
  __syncthreads();                         // all S reads done; max/sum visible
  {
    float m_gl = maxw[nh*32 + l32][0];
    #pragma unroll
    for (int j=1;j<4;j++) m_gl = fmaxf(m_gl, maxw[nh*32 + l32][j]);
    float s_gl = 0.f;
    #pragma unroll
    for (int j=0;j<4;j++) s_gl += sumw[nh*32 + l32][j] * __expf(maxw[nh*32 + l32][j] - m_gl);
    if (kq == 0 && lane < 32) sgl_lds[nh*32 + lane] = s_gl;
    float f = __expf(mrun - m_gl);
    float* scr = (float*)S;
    #pragma unroll
    for (int g=0; g<16; ++g){
      const int rowl = (g&3) + 8*(g>>2) + 4*h32;
      float fr = __shfl(f, rowl);
      scr[(size_t)(kq*2 + nh)*2048 + (size_t)g*64 + lane]      = o0[g]*fr;
      scr[(size_t)(kq*2 + nh)*2048 + (size_t)(16+g)*64 + lane] = o1[g]*fr;
    }
  }
  __syncthreads();

  // ---- reduce 4 partials + epilogue ----
  {
    const float* scr = (const float*)S;
    const int n_g = t >> 3, d0 = (t & 7)*8;
    const int nh_r = n_g >> 5, nl = n_g & 31;
    const int h32r = (nl >> 2) & 1;
    const int rr = nl - 4*h32r;
    const int g = (rr & 3) | ((rr >> 3) << 2);
    const float sdiv = sgl_lds[n_g];
    float* op = outp + (size_t)b*2048*64;
    const float* hp = hf32 + (size_t)b*2048*64;
    const float* cp = oc_in + (size_t)b*2048*64;
    #pragma unroll
    for (int j=0;j<8;j++){
      const int d = d0 + j;
      const int dt = d >> 5;
      const int lanei = (d & 31) + 32*h32r;
      float v = 0.f;
      #pragma unroll
      for (int kqr=0; kqr<4; ++kqr)
        v += scr[(size_t)(kqr*2 + nh_r)*2048 + (size_t)(dt*16 + g)*64 + lanei];
      v /= sdiv;
      size_t idx = (size_t)(n0 + n_g)*64 + d;
      if (fin) v = 0.8f*hp[idx] - 0.1f*cp[idx] + 0.1f*v;
      op[idx] = v;
    }
  }
}

// ---------------------------------------------------------------------------
extern "C" void kernel_launch(void* const* d_in, const int* in_sizes, int n_in,
                              void* d_out, int out_size, void* d_ws, size_t ws_size,
                              hipStream_t stream) {
  const float* x     = (const float*)d_in[0];
  const float* state = (const float*)d_in[1];
  const float* E     = (const float*)d_in[2];
  const float* Wc    = (const float*)d_in[3];
  const float* Wd    = (const float*)d_in[4];
  const float* gw    = (const float*)d_in[5];
  const float* gb    = (const float*)d_in[6];
  const float* uw    = (const float*)d_in[7];
  const float* ub    = (const float*)d_in[8];

  // workspace layout (bytes). Total 73,662,464 B = 70.2 MB.
  char* base = (char*)d_ws;
  u16*   P    = (u16*)(base + 0);           //  8,388,608  (dead after 2nd k_conv)
  u32*   mp2  = (u32*)(base + 0);           //    524,288  (aliases P; written after P dead)
  u32*   mn2  = (u32*)(base + 524288);      //    524,288  (aliases P)
  u8*    msk  = (u8*) (base + 8388608);     //  4,194,304
  u8*    Wc8  = (u8*) (base + 12582912);    //  4,194,304
  u8*    Wd8  = (u8*) (base + 16777216);    //  4,194,304
  u16*   hb16 = (u16*)(base + 20971520);    //  4,194,304
  u8*    ht8p = (u8*) (base + 25165824);    //  2,097,152
  u16*   hfm  = (u16*)(base + 27262976);    //  4,194,304
  float* c1x  = (float*)(base + 31457280);  //    262,144
  float* c1s  = (float*)(base + 31719424);  //  8,388,608
  float* zs   = (float*)(base + 40108032);  //  8,388,608
  float* rws  = (float*)(base + 48496640);  //  8,388,608
  float* c2s  = (float*)(base + 56885248);  //  8,388,608
  float* h    = (float*)(base + 65273856);  //  8,388,608
  float* oc   = c1s;                        // dead after k_gate
  float* od   = c2s;                        // dead after k_upd (unused placeholder)

  k_w8<<<dim3(32,32,2), 256, 0, stream>>>(Wc, Wd, Wc8, Wd8);
  k_P<<<2048, 256, 0, stream>>>(E, P, msk);
  k_c1x<<<dim3(32,16), 128, 0, stream>>>(P, x, c1x);
  k_conv<<<dim3(32,16), 256, 0, stream>>>(P, state, c1s);
  k_gate<<<2048, 256, 0, stream>>>(E, gw, gb, x, state, c1x, c1s, zs, rws);
  k_conv<<<dim3(32,16), 256, 0, stream>>>(P, zs, c2s);
  k_upd<<<2048, 256, 0, stream>>>(E, uw, ub, x, state, zs, c1x, c2s, rws, h);
  k_hcvt<<<dim3(32,16), 256, 0, stream>>>(h, hb16, ht8p, hfm);
  k_mbits<<<dim3(2048,8), 256, 0, stream>>>(msk, mp2, mn2);   // P dead by now

  const int deg_lds = 64*SROW8;   // 131,584 B dynamic (+~2.3 KB static)
  hipFuncSetAttribute((const void*)k_deg, hipFuncAttributeMaxDynamicSharedMemorySize, deg_lds);
  // dispatch 1: connect mask — only Wc8 hot in every XCD L2
  k_deg<<<512, 512, deg_lds, stream>>>(mp2, hb16, Wc8, ht8p, hfm, h, h, oc, 0);
  // dispatch 2: disconnect mask — only Wd8 hot; fused final epilogue -> d_out
  k_deg<<<512, 512, deg_lds, stream>>>(mn2, hb16, Wd8, ht8p, hfm, h, oc, (float*)d_out, 1);
}

// Round 6
// 1231.658 us; speedup vs baseline: 1.5339x; 1.0205x over previous
//
#include <hip/hip_runtime.h>
#include <hip/hip_bf16.h>

typedef unsigned short u16;
typedef unsigned int   u32;
typedef unsigned char  u8;

typedef __attribute__((ext_vector_type(8))) short bf16x8;
typedef __attribute__((ext_vector_type(4))) float f32x4;
typedef __attribute__((ext_vector_type(16))) float f32x16;

static __device__ __forceinline__ float bf2f(u16 u){ return __uint_as_float(((u32)u)<<16); }
static __device__ __forceinline__ u16 f2bf(float f){
  u32 u = __float_as_uint(f);
  u32 r = (u + 0x7fff + ((u>>16)&1)) >> 16;   // RNE; inputs finite
  return (u16)r;
}

// fp8 e4m3 (OCP) helpers — HW cvt, saturating via pre-clamp
static __device__ __forceinline__ u8 f2fp8(float v){
  v = fminf(440.f, fmaxf(-440.f, v));
  return (u8)(__builtin_amdgcn_cvt_pk_fp8_f32(v, 0.f, 0, false) & 0xff);
}
static __device__ __forceinline__ u32 pk4_fp8(float a, float b, float c, float d){
  int w = __builtin_amdgcn_cvt_pk_fp8_f32(a, b, 0, false);
  w = __builtin_amdgcn_cvt_pk_fp8_f32(c, d, w, true);
  return (u32)w;
}

static __device__ __forceinline__ f32x4 mfma_bf16(bf16x8 a, bf16x8 b, f32x4 c){
  return __builtin_amdgcn_mfma_f32_16x16x32_bf16(a, b, c, 0, 0, 0);
}
static __device__ __forceinline__ f32x16 mfma_fp8_32(long a, long b, f32x16 c){
  return __builtin_amdgcn_mfma_f32_32x32x16_fp8_fp8(a, b, c, 0, 0, 0);
}
static __device__ __forceinline__ long lo64(uint4 v){ return (long)(((unsigned long long)v.y<<32) | v.x); }
static __device__ __forceinline__ long hi64(uint4 v){ return (long)(((unsigned long long)v.w<<32) | v.z); }
static __device__ __forceinline__ long mklong(u32 lo, u32 hi){ return (long)(((unsigned long long)hi<<32) | lo); }

// ---------------------------------------------------------------------------
// K-w8: W f32 [m][k] -> fp8 packed, 1KB block per (pt=m/64, kt=k/32, mcp):
//   byte at lane*16 + sel*8 + j = W[pt*64 + (mcp*2+sel)*16 + (lane>>5)*8 + j][kt*32 + (lane&31)]
// Serves BOTH as 32x32x16 B-frag (m x k) and as A-frag of W^T (k x m).
// grid (32,32,2), block 256.
// ---------------------------------------------------------------------------
__global__ void k_w8(const float* __restrict__ Wc, const float* __restrict__ Wd,
                     u8* __restrict__ Wc8, u8* __restrict__ Wd8){
  __shared__ float tile[64][65];
  const float* src = blockIdx.z ? Wd : Wc;
  u8* dst = blockIdx.z ? Wd8 : Wc8;
  const int m0 = blockIdx.x*64, k0 = blockIdx.y*64;
  const int t = threadIdx.x, r = t & 63, cc = t >> 6;
  #pragma unroll
  for (int j=0;j<4;j++){
    float4 v = *(const float4*)&src[(size_t)(m0+r)*2048 + k0 + cc*16 + j*4];
    tile[r][cc*16+j*4+0]=v.x; tile[r][cc*16+j*4+1]=v.y;
    tile[r][cc*16+j*4+2]=v.z; tile[r][cc*16+j*4+3]=v.w;
  }
  __syncthreads();
  const int lane = t & 63, sub = t >> 6;     // sub 0..3
  const int kth = sub & 1, mcp = sub >> 1;
  const int kl = kth*32 + (lane & 31);       // k within 64-tile
  const int ml = mcp*32 + (lane >> 5)*8;     // m base within 64-tile
  u32 b0 = pk4_fp8(16.f*tile[ml+ 0][kl], 16.f*tile[ml+ 1][kl], 16.f*tile[ml+ 2][kl], 16.f*tile[ml+ 3][kl]);
  u32 b1 = pk4_fp8(16.f*tile[ml+ 4][kl], 16.f*tile[ml+ 5][kl], 16.f*tile[ml+ 6][kl], 16.f*tile[ml+ 7][kl]);
  u32 b2 = pk4_fp8(16.f*tile[ml+16][kl], 16.f*tile[ml+17][kl], 16.f*tile[ml+18][kl], 16.f*tile[ml+19][kl]);
  u32 b3 = pk4_fp8(16.f*tile[ml+20][kl], 16.f*tile[ml+21][kl], 16.f*tile[ml+22][kl], 16.f*tile[ml+23][kl]);
  const int pt = m0 >> 6, kt = (k0 >> 5) + kth;
  u8* dbase = dst + (size_t)((pt*64 + kt)*2 + mcp)*1024 + lane*16;
  *(uint4*)dbase = make_uint4(b0, b1, b2, b3);
}

// ---------------------------------------------------------------------------
// K-hcvt: h f32 [b][m][64] -> hb16 (bf16 row-major), hfm (bf16 frag-major B for
// phase 1), ht8p (fp8 32x32x16-B frags: addr (k16*2 + dt)*512 + lane*8 + j ->
// h[k16*16 + (lane>>5)*8 + j][dt*32 + (lane&31)]). grid (32,16), block 256.
// ---------------------------------------------------------------------------
__global__ void k_hcvt(const float* __restrict__ h, u16* __restrict__ hb16,
                       u8* __restrict__ ht8p, u16* __restrict__ hfm){
  __shared__ float tile[64][65];
  const int k0 = blockIdx.x*64, b = blockIdx.y;
  const int t = threadIdx.x, r = t & 63, cc = t >> 6;
  const float* src = h + ((size_t)b*2048 + k0)*64;
  u32 hw[8];
  #pragma unroll
  for (int j=0;j<4;j++){
    float4 v = *(const float4*)&src[(size_t)r*64 + cc*16 + j*4];
    tile[r][cc*16+j*4+0]=v.x; tile[r][cc*16+j*4+1]=v.y;
    tile[r][cc*16+j*4+2]=v.z; tile[r][cc*16+j*4+3]=v.w;
    hw[2*j]   = (u32)f2bf(v.x) | ((u32)f2bf(v.y)<<16);
    hw[2*j+1] = (u32)f2bf(v.z) | ((u32)f2bf(v.w)<<16);
  }
  u16* hp = hb16 + (((size_t)b*2048 + k0 + r)*64 + cc*16);
  *(uint4*)hp     = make_uint4(hw[0],hw[1],hw[2],hw[3]);
  *(uint4*)(hp+8) = make_uint4(hw[4],hw[5],hw[6],hw[7]);
  __syncthreads();
  {
    // ht8p: 32x32x16 B-frag layout for out-MFMA (k x d)
    const int lane = t & 63, sub = cc;          // sub = local k16 index 0..3
    const int k16 = (k0 >> 4) + sub;
    const int lr = sub*16 + ((lane >> 5) << 3); // local row in tile
    const int d0 = lane & 31;
    #pragma unroll
    for (int dt=0; dt<2; ++dt){
      const int d = dt*32 + d0;
      u32 w0 = pk4_fp8(tile[lr+0][d], tile[lr+1][d], tile[lr+2][d], tile[lr+3][d]);
      u32 w1 = pk4_fp8(tile[lr+4][d], tile[lr+5][d], tile[lr+6][d], tile[lr+7][d]);
      *(uint2*)(ht8p + (size_t)b*131072 + (size_t)(k16*2 + dt)*512 + lane*8) = make_uint2(w0, w1);
    }
  }
  {
    const int col = k0 + r, ks = cc >> 1, q0 = (cc & 1)*2;
    const int ctg = col >> 4, lcv = col & 15;
    u16* fbase = hfm + (size_t)b*131072 + (size_t)ks*65536 + ((size_t)ctg*64)*8;
    #pragma unroll
    for (int qq=0; qq<2; ++qq){
      int q = q0 + qq;
      u32 p0 = (u32)f2bf(tile[r][ks*32+q*8+0]) | ((u32)f2bf(tile[r][ks*32+q*8+1])<<16);
      u32 p1 = (u32)f2bf(tile[r][ks*32+q*8+2]) | ((u32)f2bf(tile[r][ks*32+q*8+3])<<16);
      u32 p2 = (u32)f2bf(tile[r][ks*32+q*8+4]) | ((u32)f2bf(tile[r][ks*32+q*8+5])<<16);
      u32 p3 = (u32)f2bf(tile[r][ks*32+q*8+6]) | ((u32)f2bf(tile[r][ks*32+q*8+7])<<16);
      *(uint4*)(fbase + (size_t)(q*16 + lcv)*8) = make_uint4(p0,p1,p2,p3);
    }
  }
}

// ---------------------------------------------------------------------------
// K1: row n of A = E E^T. sign-mask (1 pos, 2 neg) + P=softmax(relu) bf16.
// ---------------------------------------------------------------------------
__global__ void k_P(const float* __restrict__ E, u16* __restrict__ P, u8* __restrict__ msk){
  __shared__ float Ew[16];
  __shared__ float arow[2048];
  __shared__ float red[4];
  const int t = threadIdx.x, n = blockIdx.x;
  if (t < 16) Ew[t] = E[n*16 + t];
  __syncthreads();
  float lmax = 0.f;
  for (int i=0;i<8;i++){
    int m = t + 256*i;
    const float* ep = E + m*16;
    float dot = 0.f;
    #pragma unroll
    for (int d=0; d<16; ++d) dot += Ew[d]*ep[d];
    msk[n*2048 + m] = dot > 0.f ? (u8)1 : (dot < 0.f ? (u8)2 : (u8)0);
    float ar = fmaxf(dot, 0.f);
    arow[m] = ar;
    lmax = fmaxf(lmax, ar);
  }
  for (int o=1;o<64;o<<=1) lmax = fmaxf(lmax, __shfl_xor(lmax, o));
  if ((t&63)==0) red[t>>6] = lmax;
  __syncthreads();
  float gmax = fmaxf(fmaxf(red[0],red[1]), fmaxf(red[2],red[3]));
  __syncthreads();
  float lsum = 0.f;
  for (int i=0;i<8;i++){
    int m = t + 256*i;
    float e = expf(arow[m] - gmax);
    arow[m] = e;
    lsum += e;
  }
  for (int o=1;o<64;o<<=1) lsum += __shfl_xor(lsum, o);
  if ((t&63)==0) red[t>>6] = lsum;
  __syncthreads();
  float inv = 1.f/(red[0]+red[1]+red[2]+red[3]);
  for (int i=0;i<8;i++){
    int m = t + 256*i;
    P[n*2048 + m] = f2bf(arow[m]*inv);
  }
}

// ---------------------------------------------------------------------------
// K-mbits: msk u8 [n][m] -> transposed bitmaps mp2/mn2 u32 [n/32][m].
// grid (2048, 8), block 256.
// ---------------------------------------------------------------------------
__global__ void k_mbits(const u8* __restrict__ msk, u32* __restrict__ mp2, u32* __restrict__ mn2){
  const int m = blockIdx.x, nb = blockIdx.y*256;
  const int t = threadIdx.x, w = t>>6, lane = t&63;
  u8 v = msk[(size_t)(nb + t)*2048 + m];
  unsigned long long bp = __ballot(v == (u8)1);
  unsigned long long bn = __ballot(v == (u8)2);
  if (lane == 0){
    int wi = (nb + w*64) >> 5;
    mp2[(size_t)wi*2048 + m]     = (u32)bp;
    mp2[(size_t)(wi+1)*2048 + m] = (u32)(bp>>32);
    mn2[(size_t)wi*2048 + m]     = (u32)bn;
    mn2[(size_t)(wi+1)*2048 + m] = (u32)(bn>>32);
  }
}

// ---------------------------------------------------------------------------
// K2x: c1x[b,n,c] = sum_m P[n,m] * x[b,m,c]
// ---------------------------------------------------------------------------
__global__ void k_c1x(const u16* __restrict__ P, const float* __restrict__ x, float* __restrict__ c1x){
  const int t = threadIdx.x;
  const int r = t>>1, c = t&1;
  const int n = blockIdx.x*64 + r, b = blockIdx.y;
  const u16* pr = P + (size_t)n*2048;
  const float* xb = x + (size_t)b*2048*2 + c;
  float acc = 0.f;
  for (int m=0;m<2048;m+=4){
    acc += bf2f(pr[m+0])*xb[(m+0)*2];
    acc += bf2f(pr[m+1])*xb[(m+1)*2];
    acc += bf2f(pr[m+2])*xb[(m+2)*2];
    acc += bf2f(pr[m+3])*xb[(m+3)*2];
  }
  c1x[((size_t)b*2048 + n)*2 + c] = acc;
}

// ---------------------------------------------------------------------------
// K2: Y[b,n,d] = sum_m P[n,m] * Z[b,m,d], Z f32 [B,N,64]. 64x64 tile.
// ---------------------------------------------------------------------------
__global__ void k_conv(const u16* __restrict__ P, const float* __restrict__ Z, float* __restrict__ Y){
  __shared__ float Pt[16][68];
  __shared__ float Zt[16][68];
  const int t = threadIdx.x;
  const int tr = t>>4, tc = t&15;
  const int n0 = blockIdx.x*64, b = blockIdx.y;
  float acc[4][4] = {};
  for (int mt=0; mt<128; ++mt){
    int m0 = mt*16;
    {
      int r = t>>2, c4 = (t&3)*4;
      const u16* pp = P + (size_t)(n0+r)*2048 + m0 + c4;
      u32 p0 = *(const u32*)pp, p1v = *(const u32*)(pp+2);
      Pt[c4+0][r]=bf2f((u16)p0);  Pt[c4+1][r]=bf2f((u16)(p0>>16));
      Pt[c4+2][r]=bf2f((u16)p1v); Pt[c4+3][r]=bf2f((u16)(p1v>>16));
      int mm = t>>4, d0 = (t&15)*4;
      float4 zv = *(const float4*)&Z[((size_t)b*2048 + m0+mm)*64 + d0];
      Zt[mm][d0+0]=zv.x; Zt[mm][d0+1]=zv.y; Zt[mm][d0+2]=zv.z; Zt[mm][d0+3]=zv.w;
    }
    __syncthreads();
    #pragma unroll
    for (int mm=0; mm<16; ++mm){
      float4 a  = *(const float4*)&Pt[mm][tr*4];
      float4 bz = *(const float4*)&Zt[mm][tc*4];
      acc[0][0]+=a.x*bz.x; acc[0][1]+=a.x*bz.y; acc[0][2]+=a.x*bz.z; acc[0][3]+=a.x*bz.w;
      acc[1][0]+=a.y*bz.x; acc[1][1]+=a.y*bz.y; acc[1][2]+=a.y*bz.z; acc[1][3]+=a.y*bz.w;
      acc[2][0]+=a.z*bz.x; acc[2][1]+=a.z*bz.y; acc[2][2]+=a.z*bz.z; acc[2][3]+=a.z*bz.w;
      acc[3][0]+=a.w*bz.x; acc[3][1]+=a.w*bz.y; acc[3][2]+=a.w*bz.z; acc[3][3]+=a.w*bz.w;
    }
    __syncthreads();
  }
  #pragma unroll
  for (int i=0;i<4;i++){
    float4 v = make_float4(acc[i][0],acc[i][1],acc[i][2],acc[i][3]);
    *(float4*)&Y[((size_t)b*2048 + n0 + tr*4 + i)*64 + tc*4] = v;
  }
}

// ---------------------------------------------------------------------------
// K3: gate SAGC -> zs = z*state, rws = r. One block per node n.
// ---------------------------------------------------------------------------
__global__ void k_gate(const float* __restrict__ E, const float* __restrict__ gw, const float* __restrict__ gb,
                       const float* __restrict__ x, const float* __restrict__ state,
                       const float* __restrict__ c1x, const float* __restrict__ c1s,
                       float* __restrict__ zs, float* __restrict__ rws){
  __shared__ float Ew[16];
  __shared__ float bnv[128];
  __shared__ float Wn[2][66][64];
  __shared__ float xg4[4][2][66];
  const int t = threadIdx.x, n = blockIdx.x;
  if (t < 16) Ew[t] = E[n*16 + t];
  __syncthreads();
  if (t < 128){
    float a = 0.f;
    #pragma unroll
    for (int e=0;e<16;e++) a += Ew[e]*gb[e*128 + t];
    bnv[t] = a;
  }
  for (int half=0; half<2; ++half){
    for (int idx=t; idx<8448; idx+=256){
      int o = idx & 63, rest = idx>>6, i = rest % 66, k = rest / 66;
      float a = 0.f;
      #pragma unroll
      for (int e=0;e<16;e++) a += Ew[e]*gw[((e*2+k)*66 + i)*128 + half*64 + o];
      Wn[k][i][o] = a;
    }
    __syncthreads();
    for (int bb=0; bb<4; ++bb){
      for (int idx=t; idx<528; idx+=256){
        int bi = idx/132, rem = idx%132, k = rem/66, i = rem%66;
        int b = bb*4 + bi;
        float v;
        if (k==0) v = (i<2) ? x[((size_t)b*2048+n)*2 + i] : state[((size_t)b*2048+n)*64 + (i-2)];
        else      v = (i<2) ? c1x[((size_t)b*2048+n)*2 + i] : c1s[((size_t)b*2048+n)*64 + (i-2)];
        xg4[bi][k][i] = v;
      }
      __syncthreads();
      {
        int bi = t>>6, o = t&63, b = bb*4 + bi;
        float a = 0.f;
        #pragma unroll
        for (int k=0;k<2;k++)
          for (int i=0;i<66;i++) a += xg4[bi][k][i]*Wn[k][i][o];
        a += bnv[half*64 + o];
        float s = 1.f/(1.f + expf(-a));
        if (half==0) zs[((size_t)b*2048+n)*64 + o] = s*state[((size_t)b*2048+n)*64 + o];
        else         rws[((size_t)b*2048+n)*64 + o] = s;
      }
      __syncthreads();
    }
  }
}

// ---------------------------------------------------------------------------
// K3b: update SAGC -> hc -> h = r*state + (1-r)*hc.
// ---------------------------------------------------------------------------
__global__ void k_upd(const float* __restrict__ E, const float* __restrict__ uw, const float* __restrict__ ub,
                      const float* __restrict__ x, const float* __restrict__ state,
                      const float* __restrict__ zs, const float* __restrict__ c1x, const float* __restrict__ c2s,
                      const float* __restrict__ rws, float* __restrict__ h){
  __shared__ float Ew[16];
  __shared__ float bnu[64];
  __shared__ float Wn[2][66][64];
  __shared__ float xg4[4][2][66];
  const int t = threadIdx.x, n = blockIdx.x;
  if (t < 16) Ew[t] = E[n*16 + t];
  __syncthreads();
  if (t < 64){
    float a = 0.f;
    #pragma unroll
    for (int e=0;e<16;e++) a += Ew[e]*ub[e*64 + t];
    bnu[t] = a;
  }
  for (int idx=t; idx<8448; idx+=256){
    int o = idx & 63, rest = idx>>6, i = rest % 66, k = rest / 66;
    float a = 0.f;
    #pragma unroll
    for (int e=0;e<16;e++) a += Ew[e]*uw[((e*2+k)*66 + i)*64 + o];
    Wn[k][i][o] = a;
  }
  __syncthreads();
  for (int bb=0; bb<4; ++bb){
    for (int idx=t; idx<528; idx+=256){
      int bi = idx/132, rem = idx%132, k = rem/66, i = rem%66;
      int b = bb*4 + bi;
      float v;
      if (k==0) v = (i<2) ? x[((size_t)b*2048+n)*2 + i] : zs[((size_t)b*2048+n)*64 + (i-2)];
      else      v = (i<2) ? c1x[((size_t)b*2048+n)*2 + i] : c2s[((size_t)b*2048+n)*64 + (i-2)];
      xg4[bi][k][i] = v;
    }
    __syncthreads();
    {
      int bi = t>>6, o = t&63, b = bb*4 + bi;
      float a = 0.f;
      #pragma unroll
      for (int k=0;k<2;k++)
        for (int i=0;i<66;i++) a += xg4[bi][k][i]*Wn[k][i][o];
      float hc = tanhf(a + bnu[o]);
      float rv = rws[((size_t)b*2048+n)*64 + o];
      h[((size_t)b*2048+n)*64 + o] = rv*state[((size_t)b*2048+n)*64 + o] + (1.f - rv)*hc;
    }
    __syncthreads();
  }
}

// ---------------------------------------------------------------------------
// K5: fused degrees — R13: R12 flash structure + (1) W double-buffer prefetch
// in the logit loop (hides ~220cy L2 latency under the 16-MFMA burst; R12 was
// load->use serialized, R3 proved the pattern) and (2) s_setprio(1) around the
// logit MFMA loop (T5: waves drift into MFMA-phase vs softmax-VALU-phase; bias
// the CU scheduler to keep the matrix pipe fed). Geometry/math identical to
// R12: 512 blocks x 512 thr, 64-row S (131.6 KB), online softmax, LSE merge.
// Watch: VGPR ~216-248 (cap 256 @ (512,2)); WRITE_SIZE >100MB => spill, revert.
// ---------------------------------------------------------------------------
#define SROW8 2056

__global__ void __launch_bounds__(512,2) k_deg(
    const u32* __restrict__ mbits, const u16* __restrict__ hb16,
    const u8* __restrict__ W8,
    const u8* __restrict__ ht8p, const u16* __restrict__ hfm,
    const float* __restrict__ hf32, const float* __restrict__ oc_in,
    float* __restrict__ outp, int fin){
  extern __shared__ u8 S[];
  __shared__ float maxw[64][4];
  __shared__ float sumw[64][4];
  __shared__ float sgl_lds[64];
  const int t = threadIdx.x;
  const int w = t >> 6, lane = t & 63, lc = lane & 15, q = lane >> 4;
  const int l32 = lane & 31, h32 = lane >> 5;
  const int id = blockIdx.x;
  const int b = id >> 5, n0 = (id & 31) * 64;
  const int p0 = (id >> 3) & 31;          // per-CU-within-XCD rotation offset
  const u32* mrow0 = mbits + (size_t)(n0 >> 5)*2048;
  const u32* mrow1 = mrow0 + 2048;
  const u16* hbb = hb16 + (size_t)b*2048*64;
  const u16* hfb = hfm + (size_t)b*131072;
  const u8* htb = ht8p + (size_t)b*131072;

  // ---- phase 1: S[r][m] = fp8( (bit ? h_n.h_m : 0) / 8 ), 64 rows ----
  {
    const int c0 = p0 & 15;
    bf16x8 A[4][2];
    #pragma unroll
    for (int rt=0; rt<4; ++rt)
      #pragma unroll
      for (int ks=0; ks<2; ++ks)
        A[rt][ks] = *(const bf16x8*)&hbb[(size_t)(n0 + rt*16 + lc)*64 + ks*32 + q*8];
    int ctg0 = w*16 + c0;
    bf16x8 B0c = *(const bf16x8*)(hfb + (size_t)ctg0*512 + lane*8);
    bf16x8 B1c = *(const bf16x8*)(hfb + 65536 + (size_t)ctg0*512 + lane*8);
    u32 m0c = mrow0[ctg0*16 + lc], m1c = mrow1[ctg0*16 + lc];
    #pragma unroll 1
    for (int ct=0; ct<16; ++ct){
      const int ctg  = w*16 + ((ct + c0) & 15);
      const int ctgn = w*16 + ((ct + 1 + c0) & 15);
      bf16x8 B0n = *(const bf16x8*)(hfb + (size_t)ctgn*512 + lane*8);
      bf16x8 B1n = *(const bf16x8*)(hfb + 65536 + (size_t)ctgn*512 + lane*8);
      u32 m0n = mrow0[ctgn*16 + lc], m1n = mrow1[ctgn*16 + lc];
      const int mcol = ctg*16 + lc;
      f32x4 a[4];
      #pragma unroll
      for (int rt=0; rt<4; ++rt){
        a[rt] = (f32x4){0.f,0.f,0.f,0.f};
        a[rt] = mfma_bf16(A[rt][0], B0c, a[rt]);
        a[rt] = mfma_bf16(A[rt][1], B1c, a[rt]);
      }
      #pragma unroll
      for (int rt=0; rt<4; ++rt){
        const u32 mw = (rt < 2) ? m0c : m1c;
        #pragma unroll
        for (int i=0;i<4;i++){
          const int row = rt*16 + q*4 + i;
          float v = ((mw >> (row & 31)) & 1u) ? a[rt][i]*0.125f : 0.f;
          S[row*SROW8 + mcol] = f2fp8(v);
        }
      }
      B0c = B0n; B1c = B1n; m0c = m0n; m1c = m1n;
    }
  }
  __syncthreads();

  // ---- fused phases 2+3+4: online softmax + PV, barrier-free per wave ----
  // wave w: n-half nh = w>>2 (rows nh*32..+32), k-slice kq = w&3 (cols kq*512..+512)
  const int nh = w >> 2, kq = w & 3;
  const u8* sbase = S + (size_t)(nh*32 + l32)*SROW8 + h32*8;
  const u8* wl = W8 + lane*16;
  f32x16 o0 = (f32x16)(0.f), o1 = (f32x16)(0.f);
  float mrun = -1e30f, srun = 0.f;
  const float LN256 = 5.545177444479562f;
  #pragma unroll 1
  for (int si = 0; si < 4; ++si){
    const int ktb = kq*16 + si*4;
    f32x16 L[4];
    #pragma unroll
    for (int tt=0; tt<4; ++tt) L[tt] = (f32x16)(0.f);
    // prologue: prefetch first pt's W blocks
    uint4 wv[8];
    {
      const int pt0 = p0 & 31;
      #pragma unroll
      for (int tt=0; tt<4; ++tt){
        wv[tt*2+0] = *(const uint4*)(wl + (size_t)(((pt0*64 + ktb+tt)*2 + 0))*1024);
        wv[tt*2+1] = *(const uint4*)(wl + (size_t)(((pt0*64 + ktb+tt)*2 + 1))*1024);
      }
    }
    __builtin_amdgcn_s_setprio(1);
    #pragma unroll 1
    for (int pti = 0; pti < 32; ++pti){
      const int pt  = (pti + p0) & 31;
      const int ptn = (pti + 1 + p0) & 31;
      long b0 = *(const long*)(sbase + pt*64 +  0);
      long b1 = *(const long*)(sbase + pt*64 + 16);
      long b2 = *(const long*)(sbase + pt*64 + 32);
      long b3 = *(const long*)(sbase + pt*64 + 48);
      uint4 wn[8];
      #pragma unroll
      for (int tt=0; tt<4; ++tt){
        wn[tt*2+0] = *(const uint4*)(wl + (size_t)(((ptn*64 + ktb+tt)*2 + 0))*1024);
        wn[tt*2+1] = *(const uint4*)(wl + (size_t)(((ptn*64 + ktb+tt)*2 + 1))*1024);
      }
      #pragma unroll
      for (int tt=0; tt<4; ++tt) L[tt] = mfma_fp8_32(lo64(wv[tt*2+0]), b0, L[tt]);
      #pragma unroll
      for (int tt=0; tt<4; ++tt) L[tt] = mfma_fp8_32(hi64(wv[tt*2+0]), b1, L[tt]);
      #pragma unroll
      for (int tt=0; tt<4; ++tt) L[tt] = mfma_fp8_32(lo64(wv[tt*2+1]), b2, L[tt]);
      #pragma unroll
      for (int tt=0; tt<4; ++tt) L[tt] = mfma_fp8_32(hi64(wv[tt*2+1]), b3, L[tt]);
      #pragma unroll
      for (int i=0; i<8; ++i) wv[i] = wn[i];
    }
    __builtin_amdgcn_s_setprio(0);
    // chunk max (logit units = 0.5*acc); n = l32 per lane
    float cmax = L[0][0];
    #pragma unroll
    for (int tt=0; tt<4; ++tt)
      #pragma unroll
      for (int g=0; g<16; ++g) cmax = fmaxf(cmax, L[tt][g]);
    cmax = fmaxf(cmax, __shfl_xor(cmax, 32));
    float mnew = fmaxf(mrun, 0.5f*cmax);
    float sc = __expf(mrun - mnew);
    srun *= sc;
    // rescale out (rows = n): pull per-row factor from lane rowl
    #pragma unroll
    for (int g=0; g<16; ++g){
      const int rowl = (g&3) + 8*(g>>2) + 4*h32;
      float fr = __shfl(sc, rowl);
      o0[g] *= fr; o1[g] *= fr;
    }
    float cs = 0.f;
    #pragma unroll
    for (int tt=0; tt<4; ++tt){
      float p[16];
      #pragma unroll
      for (int g=0; g<16; ++g){
        p[g] = __expf(0.5f*L[tt][g] - mnew + LN256);   // 256-scaled
        cs += p[g];
      }
      u32 qA = pk4_fp8(p[0],p[1],p[2],p[3]);
      u32 qB = pk4_fp8(p[4],p[5],p[6],p[7]);
      u32 qC = pk4_fp8(p[8],p[9],p[10],p[11]);
      u32 qD = pk4_fp8(p[12],p[13],p[14],p[15]);
      u32 xA = __shfl_xor(qA, 32), xB = __shfl_xor(qB, 32);
      u32 xC = __shfl_xor(qC, 32), xD = __shfl_xor(qD, 32);
      // A-frags of P (n x k): k-chunk0 = k 0..15 of tile, chunk1 = 16..31
      long pf0 = h32 ? mklong(xB, qB) : mklong(qA, xA);
      long pf1 = h32 ? mklong(xD, qD) : mklong(qC, xC);
      const int kt = ktb + tt;
      long h00 = *(const long*)(htb + (size_t)((kt*2+0)*2 + 0)*512 + lane*8);
      long h01 = *(const long*)(htb + (size_t)((kt*2+0)*2 + 1)*512 + lane*8);
      long h10 = *(const long*)(htb + (size_t)((kt*2+1)*2 + 0)*512 + lane*8);
      long h11 = *(const long*)(htb + (size_t)((kt*2+1)*2 + 1)*512 + lane*8);
      o0 = mfma_fp8_32(pf0, h00, o0);
      o1 = mfma_fp8_32(pf0, h01, o1);
      o0 = mfma_fp8_32(pf1, h10, o0);
      o1 = mfma_fp8_32(pf1, h11, o1);
    }
    cs += __shfl_xor(cs, 32);
    srun += cs;
    mrun = mnew;
  }

  // ---- merge: log-sum-exp combine of 4 k-slices per n-half ----
  if (lane < 32){
    maxw[nh*32 + lane][kq] = mrun;
    sumw[nh*32 + lane][kq] = srun;
  }
  __syncthreads();                         // all S reads done; max/sum visible
  {
    float m_gl = maxw[nh*32 + l32][0];
    #pragma unroll
    for (int j=1;j<4;j++) m_gl = fmaxf(m_gl, maxw[nh*32 + l32][j]);
    float s_gl = 0.f;
    #pragma unroll
    for (int j=0;j<4;j++) s_gl += sumw[nh*32 + l32][j] * __expf(maxw[nh*32 + l32][j] - m_gl);
    if (kq == 0 && lane < 32) sgl_lds[nh*32 + lane] = s_gl;
    float f = __expf(mrun - m_gl);
    float* scr = (float*)S;
    #pragma unroll
    for (int g=0; g<16; ++g){
      const int rowl = (g&3) + 8*(g>>2) + 4*h32;
      float fr = __shfl(f, rowl);
      scr[(size_t)(kq*2 + nh)*2048 + (size_t)g*64 + lane]      = o0[g]*fr;
      scr[(size_t)(kq*2 + nh)*2048 + (size_t)(16+g)*64 + lane] = o1[g]*fr;
    }
  }
  __syncthreads();

  // ---- reduce 4 partials + epilogue ----
  {
    const float* scr = (const float*)S;
    const int n_g = t >> 3, d0 = (t & 7)*8;
    const int nh_r = n_g >> 5, nl = n_g & 31;
    const int h32r = (nl >> 2) & 1;
    const int rr = nl - 4*h32r;
    const int g = (rr & 3) | ((rr >> 3) << 2);
    const float sdiv = sgl_lds[n_g];
    float* op = outp + (size_t)b*2048*64;
    const float* hp = hf32 + (size_t)b*2048*64;
    const float* cp = oc_in + (size_t)b*2048*64;
    #pragma unroll
    for (int j=0;j<8;j++){
      const int d = d0 + j;
      const int dt = d >> 5;
      const int lanei = (d & 31) + 32*h32r;
      float v = 0.f;
      #pragma unroll
      for (int kqr=0; kqr<4; ++kqr)
        v += scr[(size_t)(kqr*2 + nh_r)*2048 + (size_t)(dt*16 + g)*64 + lanei];
      v /= sdiv;
      size_t idx = (size_t)(n0 + n_g)*64 + d;
      if (fin) v = 0.8f*hp[idx] - 0.1f*cp[idx] + 0.1f*v;
      op[idx] = v;
    }
  }
}

// ---------------------------------------------------------------------------
extern "C" void kernel_launch(void* const* d_in, const int* in_sizes, int n_in,
                              void* d_out, int out_size, void* d_ws, size_t ws_size,
                              hipStream_t stream) {
  const float* x     = (const float*)d_in[0];
  const float* state = (const float*)d_in[1];
  const float* E     = (const float*)d_in[2];
  const float* Wc    = (const float*)d_in[3];
  const float* Wd    = (const float*)d_in[4];
  const float* gw    = (const float*)d_in[5];
  const float* gb    = (const float*)d_in[6];
  const float* uw    = (const float*)d_in[7];
  const float* ub    = (const float*)d_in[8];

  // workspace layout (bytes). Total 73,662,464 B = 70.2 MB.
  char* base = (char*)d_ws;
  u16*   P    = (u16*)(base + 0);           //  8,388,608  (dead after 2nd k_conv)
  u32*   mp2  = (u32*)(base + 0);           //    524,288  (aliases P; written after P dead)
  u32*   mn2  = (u32*)(base + 524288);      //    524,288  (aliases P)
  u8*    msk  = (u8*) (base + 8388608);     //  4,194,304
  u8*    Wc8  = (u8*) (base + 12582912);    //  4,194,304
  u8*    Wd8  = (u8*) (base + 16777216);    //  4,194,304
  u16*   hb16 = (u16*)(base + 20971520);    //  4,194,304
  u8*    ht8p = (u8*) (base + 25165824);    //  2,097,152
  u16*   hfm  = (u16*)(base + 27262976);    //  4,194,304
  float* c1x  = (float*)(base + 31457280);  //    262,144
  float* c1s  = (float*)(base + 31719424);  //  8,388,608
  float* zs   = (float*)(base + 40108032);  //  8,388,608
  float* rws  = (float*)(base + 48496640);  //  8,388,608
  float* c2s  = (float*)(base + 56885248);  //  8,388,608
  float* h    = (float*)(base + 65273856);  //  8,388,608
  float* oc   = c1s;                        // dead after k_gate
  float* od   = c2s;                        // dead after k_upd (unused placeholder)

  k_w8<<<dim3(32,32,2), 256, 0, stream>>>(Wc, Wd, Wc8, Wd8);
  k_P<<<2048, 256, 0, stream>>>(E, P, msk);
  k_c1x<<<dim3(32,16), 128, 0, stream>>>(P, x, c1x);
  k_conv<<<dim3(32,16), 256, 0, stream>>>(P, state, c1s);
  k_gate<<<2048, 256, 0, stream>>>(E, gw, gb, x, state, c1x, c1s, zs, rws);
  k_conv<<<dim3(32,16), 256, 0, stream>>>(P, zs, c2s);
  k_upd<<<2048, 256, 0, stream>>>(E, uw, ub, x, state, zs, c1x, c2s, rws, h);
  k_hcvt<<<dim3(32,16), 256, 0, stream>>>(h, hb16, ht8p, hfm);
  k_mbits<<<dim3(2048,8), 256, 0, stream>>>(msk, mp2, mn2);   // P dead by now

  const int deg_lds = 64*SROW8;   // 131,584 B dynamic (+~2.3 KB static)
  hipFuncSetAttribute((const void*)k_deg, hipFuncAttributeMaxDynamicSharedMemorySize, deg_lds);
  // dispatch 1: connect mask — only Wc8 hot in every XCD L2
  k_deg<<<512, 512, deg_lds, stream>>>(mp2, hb16, Wc8, ht8p, hfm, h, h, oc, 0);
  // dispatch 2: disconnect mask — only Wd8 hot; fused final epilogue -> d_out
  k_deg<<<512, 512, deg_lds, stream>>>(mn2, hb16, Wd8, ht8p, hfm, h, oc, (float*)d_out, 1);
}

// Round 7
// 1028.545 us; speedup vs baseline: 1.8368x; 1.1975x over previous
//
#include <hip/hip_runtime.h>
#include <hip/hip_bf16.h>

typedef unsigned short u16;
typedef unsigned int   u32;
typedef unsigned char  u8;

typedef __attribute__((ext_vector_type(8))) short bf16x8;
typedef __attribute__((ext_vector_type(4))) float f32x4;
typedef __attribute__((ext_vector_type(16))) float f32x16;

static __device__ __forceinline__ float bf2f(u16 u){ return __uint_as_float(((u32)u)<<16); }
static __device__ __forceinline__ u16 f2bf(float f){
  u32 u = __float_as_uint(f);
  u32 r = (u + 0x7fff + ((u>>16)&1)) >> 16;   // RNE; inputs finite
  return (u16)r;
}

// fp8 e4m3 (OCP) helpers — HW cvt, saturating via pre-clamp
static __device__ __forceinline__ u8 f2fp8(float v){
  v = fminf(440.f, fmaxf(-440.f, v));
  return (u8)(__builtin_amdgcn_cvt_pk_fp8_f32(v, 0.f, 0, false) & 0xff);
}
static __device__ __forceinline__ u32 pk4_fp8(float a, float b, float c, float d){
  int w = __builtin_amdgcn_cvt_pk_fp8_f32(a, b, 0, false);
  w = __builtin_amdgcn_cvt_pk_fp8_f32(c, d, w, true);
  return (u32)w;
}

static __device__ __forceinline__ f32x4 mfma_bf16(bf16x8 a, bf16x8 b, f32x4 c){
  return __builtin_amdgcn_mfma_f32_16x16x32_bf16(a, b, c, 0, 0, 0);
}
static __device__ __forceinline__ f32x16 mfma_bf16_32(bf16x8 a, bf16x8 b, f32x16 c){
  return __builtin_amdgcn_mfma_f32_32x32x16_bf16(a, b, c, 0, 0, 0);
}
static __device__ __forceinline__ f32x16 mfma_fp8_32(long a, long b, f32x16 c){
  return __builtin_amdgcn_mfma_f32_32x32x16_fp8_fp8(a, b, c, 0, 0, 0);
}
static __device__ __forceinline__ long lo64(uint4 v){ return (long)(((unsigned long long)v.y<<32) | v.x); }
static __device__ __forceinline__ long hi64(uint4 v){ return (long)(((unsigned long long)v.w<<32) | v.z); }
static __device__ __forceinline__ long mklong(u32 lo, u32 hi){ return (long)(((unsigned long long)hi<<32) | lo); }

// ---------------------------------------------------------------------------
// K-w8: W f32 [m][k] -> fp8 packed, 1KB block per (pt=m/64, kt=k/32, mcp):
//   byte at lane*16 + sel*8 + j = W[pt*64 + (mcp*2+sel)*16 + (lane>>5)*8 + j][kt*32 + (lane&31)]
// Serves BOTH as 32x32x16 B-frag (m x k) and as A-frag of W^T (k x m).
// grid (32,32,2), block 256.
// ---------------------------------------------------------------------------
__global__ void k_w8(const float* __restrict__ Wc, const float* __restrict__ Wd,
                     u8* __restrict__ Wc8, u8* __restrict__ Wd8){
  __shared__ float tile[64][65];
  const float* src = blockIdx.z ? Wd : Wc;
  u8* dst = blockIdx.z ? Wd8 : Wc8;
  const int m0 = blockIdx.x*64, k0 = blockIdx.y*64;
  const int t = threadIdx.x, r = t & 63, cc = t >> 6;
  #pragma unroll
  for (int j=0;j<4;j++){
    float4 v = *(const float4*)&src[(size_t)(m0+r)*2048 + k0 + cc*16 + j*4];
    tile[r][cc*16+j*4+0]=v.x; tile[r][cc*16+j*4+1]=v.y;
    tile[r][cc*16+j*4+2]=v.z; tile[r][cc*16+j*4+3]=v.w;
  }
  __syncthreads();
  const int lane = t & 63, sub = t >> 6;     // sub 0..3
  const int kth = sub & 1, mcp = sub >> 1;
  const int kl = kth*32 + (lane & 31);       // k within 64-tile
  const int ml = mcp*32 + (lane >> 5)*8;     // m base within 64-tile
  u32 b0 = pk4_fp8(16.f*tile[ml+ 0][kl], 16.f*tile[ml+ 1][kl], 16.f*tile[ml+ 2][kl], 16.f*tile[ml+ 3][kl]);
  u32 b1 = pk4_fp8(16.f*tile[ml+ 4][kl], 16.f*tile[ml+ 5][kl], 16.f*tile[ml+ 6][kl], 16.f*tile[ml+ 7][kl]);
  u32 b2 = pk4_fp8(16.f*tile[ml+16][kl], 16.f*tile[ml+17][kl], 16.f*tile[ml+18][kl], 16.f*tile[ml+19][kl]);
  u32 b3 = pk4_fp8(16.f*tile[ml+20][kl], 16.f*tile[ml+21][kl], 16.f*tile[ml+22][kl], 16.f*tile[ml+23][kl]);
  const int pt = m0 >> 6, kt = (k0 >> 5) + kth;
  u8* dbase = dst + (size_t)((pt*64 + kt)*2 + mcp)*1024 + lane*16;
  *(uint4*)dbase = make_uint4(b0, b1, b2, b3);
}

// ---------------------------------------------------------------------------
// K-hcvt: h f32 [b][m][64] -> hb16 (bf16 row-major), hfm (bf16 frag-major B for
// phase 1), ht8p (fp8 32x32x16-B frags: addr (k16*2 + dt)*512 + lane*8 + j ->
// h[k16*16 + (lane>>5)*8 + j][dt*32 + (lane&31)]). grid (32,16), block 256.
// ---------------------------------------------------------------------------
__global__ void k_hcvt(const float* __restrict__ h, u16* __restrict__ hb16,
                       u8* __restrict__ ht8p, u16* __restrict__ hfm){
  __shared__ float tile[64][65];
  const int k0 = blockIdx.x*64, b = blockIdx.y;
  const int t = threadIdx.x, r = t & 63, cc = t >> 6;
  const float* src = h + ((size_t)b*2048 + k0)*64;
  u32 hw[8];
  #pragma unroll
  for (int j=0;j<4;j++){
    float4 v = *(const float4*)&src[(size_t)r*64 + cc*16 + j*4];
    tile[r][cc*16+j*4+0]=v.x; tile[r][cc*16+j*4+1]=v.y;
    tile[r][cc*16+j*4+2]=v.z; tile[r][cc*16+j*4+3]=v.w;
    hw[2*j]   = (u32)f2bf(v.x) | ((u32)f2bf(v.y)<<16);
    hw[2*j+1] = (u32)f2bf(v.z) | ((u32)f2bf(v.w)<<16);
  }
  u16* hp = hb16 + (((size_t)b*2048 + k0 + r)*64 + cc*16);
  *(uint4*)hp     = make_uint4(hw[0],hw[1],hw[2],hw[3]);
  *(uint4*)(hp+8) = make_uint4(hw[4],hw[5],hw[6],hw[7]);
  __syncthreads();
  {
    // ht8p: 32x32x16 B-frag layout for out-MFMA (k x d)
    const int lane = t & 63, sub = cc;          // sub = local k16 index 0..3
    const int k16 = (k0 >> 4) + sub;
    const int lr = sub*16 + ((lane >> 5) << 3); // local row in tile
    const int d0 = lane & 31;
    #pragma unroll
    for (int dt=0; dt<2; ++dt){
      const int d = dt*32 + d0;
      u32 w0 = pk4_fp8(tile[lr+0][d], tile[lr+1][d], tile[lr+2][d], tile[lr+3][d]);
      u32 w1 = pk4_fp8(tile[lr+4][d], tile[lr+5][d], tile[lr+6][d], tile[lr+7][d]);
      *(uint2*)(ht8p + (size_t)b*131072 + (size_t)(k16*2 + dt)*512 + lane*8) = make_uint2(w0, w1);
    }
  }
  {
    const int col = k0 + r, ks = cc >> 1, q0 = (cc & 1)*2;
    const int ctg = col >> 4, lcv = col & 15;
    u16* fbase = hfm + (size_t)b*131072 + (size_t)ks*65536 + ((size_t)ctg*64)*8;
    #pragma unroll
    for (int qq=0; qq<2; ++qq){
      int q = q0 + qq;
      u32 p0 = (u32)f2bf(tile[r][ks*32+q*8+0]) | ((u32)f2bf(tile[r][ks*32+q*8+1])<<16);
      u32 p1 = (u32)f2bf(tile[r][ks*32+q*8+2]) | ((u32)f2bf(tile[r][ks*32+q*8+3])<<16);
      u32 p2 = (u32)f2bf(tile[r][ks*32+q*8+4]) | ((u32)f2bf(tile[r][ks*32+q*8+5])<<16);
      u32 p3 = (u32)f2bf(tile[r][ks*32+q*8+6]) | ((u32)f2bf(tile[r][ks*32+q*8+7])<<16);
      *(uint4*)(fbase + (size_t)(q*16 + lcv)*8) = make_uint4(p0,p1,p2,p3);
    }
  }
}

// ---------------------------------------------------------------------------
// K1: row n of A = E E^T. sign-mask (1 pos, 2 neg) + P=softmax(relu) bf16.
// ---------------------------------------------------------------------------
__global__ void k_P(const float* __restrict__ E, u16* __restrict__ P, u8* __restrict__ msk){
  __shared__ float Ew[16];
  __shared__ float arow[2048];
  __shared__ float red[4];
  const int t = threadIdx.x, n = blockIdx.x;
  if (t < 16) Ew[t] = E[n*16 + t];
  __syncthreads();
  float lmax = 0.f;
  for (int i=0;i<8;i++){
    int m = t + 256*i;
    const float* ep = E + m*16;
    float dot = 0.f;
    #pragma unroll
    for (int d=0; d<16; ++d) dot += Ew[d]*ep[d];
    msk[n*2048 + m] = dot > 0.f ? (u8)1 : (dot < 0.f ? (u8)2 : (u8)0);
    float ar = fmaxf(dot, 0.f);
    arow[m] = ar;
    lmax = fmaxf(lmax, ar);
  }
  for (int o=1;o<64;o<<=1) lmax = fmaxf(lmax, __shfl_xor(lmax, o));
  if ((t&63)==0) red[t>>6] = lmax;
  __syncthreads();
  float gmax = fmaxf(fmaxf(red[0],red[1]), fmaxf(red[2],red[3]));
  __syncthreads();
  float lsum = 0.f;
  for (int i=0;i<8;i++){
    int m = t + 256*i;
    float e = expf(arow[m] - gmax);
    arow[m] = e;
    lsum += e;
  }
  for (int o=1;o<64;o<<=1) lsum += __shfl_xor(lsum, o);
  if ((t&63)==0) red[t>>6] = lsum;
  __syncthreads();
  float inv = 1.f/(red[0]+red[1]+red[2]+red[3]);
  for (int i=0;i<8;i++){
    int m = t + 256*i;
    P[n*2048 + m] = f2bf(arow[m]*inv);
  }
}

// ---------------------------------------------------------------------------
// K-mbits: msk u8 [n][m] -> transposed bitmaps mp2/mn2 u32 [n/32][m].
// grid (2048, 8), block 256.
// ---------------------------------------------------------------------------
__global__ void k_mbits(const u8* __restrict__ msk, u32* __restrict__ mp2, u32* __restrict__ mn2){
  const int m = blockIdx.x, nb = blockIdx.y*256;
  const int t = threadIdx.x, w = t>>6, lane = t&63;
  u8 v = msk[(size_t)(nb + t)*2048 + m];
  unsigned long long bp = __ballot(v == (u8)1);
  unsigned long long bn = __ballot(v == (u8)2);
  if (lane == 0){
    int wi = (nb + w*64) >> 5;
    mp2[(size_t)wi*2048 + m]     = (u32)bp;
    mp2[(size_t)(wi+1)*2048 + m] = (u32)(bp>>32);
    mn2[(size_t)wi*2048 + m]     = (u32)bn;
    mn2[(size_t)(wi+1)*2048 + m] = (u32)(bn>>32);
  }
}

// ---------------------------------------------------------------------------
// K2x: c1x[b,n,c] = sum_m P[n,m] * x[b,m,c]
// ---------------------------------------------------------------------------
__global__ void k_c1x(const u16* __restrict__ P, const float* __restrict__ x, float* __restrict__ c1x){
  const int t = threadIdx.x;
  const int r = t>>1, c = t&1;
  const int n = blockIdx.x*64 + r, b = blockIdx.y;
  const u16* pr = P + (size_t)n*2048;
  const float* xb = x + (size_t)b*2048*2 + c;
  float acc = 0.f;
  for (int m=0;m<2048;m+=4){
    acc += bf2f(pr[m+0])*xb[(m+0)*2];
    acc += bf2f(pr[m+1])*xb[(m+1)*2];
    acc += bf2f(pr[m+2])*xb[(m+2)*2];
    acc += bf2f(pr[m+3])*xb[(m+3)*2];
  }
  c1x[((size_t)b*2048 + n)*2 + c] = acc;
}

// ---------------------------------------------------------------------------
// K2 (R14): Y[b,n,d] = sum_m P[n,m] * Z[b,m,d] via bf16 MFMA with
// error-compensated split Z ~= Zhi + Zlo (combined precision ~2^-17 ~ fp32;
// P is already bf16 so accuracy == old fp32-VALU version). 64x64 tile,
// 4 waves = (nh, dh), K-chunks of 64 staged in LDS (Z transposed [d][m],
// 68-pad => 2-way-free banks). Two accs (hi/lo) keep MFMA dep-dist 2.
// grid (32,16), block 256.
// ---------------------------------------------------------------------------
__global__ void k_conv(const u16* __restrict__ P, const float* __restrict__ Z, float* __restrict__ Y){
  __shared__ u16 Pt[64][68];
  __shared__ u16 Zhi[64][68];
  __shared__ u16 Zlo[64][68];
  const int t = threadIdx.x;
  const int w = t >> 6, lane = t & 63, l32 = lane & 31, h32 = lane >> 5;
  const int nh = w & 1, dh = w >> 1;
  const int n0 = blockIdx.x*64, b = blockIdx.y;
  const int mloc = t & 63, grp = t >> 6;
  f32x16 acch = (f32x16)(0.f), accl = (f32x16)(0.f);
  for (int mc = 0; mc < 32; ++mc){
    const int m0 = mc*64;
    {
      const u16* pp = P + (size_t)(n0 + mloc)*2048 + m0 + grp*16;
      uint4 v0 = *(const uint4*)pp;
      uint4 v1 = *(const uint4*)(pp + 8);
      *(uint4*)&Pt[mloc][grp*16]     = v0;
      *(uint4*)&Pt[mloc][grp*16 + 8] = v1;
      const float* zp = Z + ((size_t)b*2048 + m0 + mloc)*64 + grp*16;
      #pragma unroll
      for (int jj = 0; jj < 4; ++jj){
        float4 zv = *(const float4*)(zp + jj*4);
        const int dd = grp*16 + jj*4;
        u16 h0 = f2bf(zv.x); Zhi[dd+0][mloc] = h0; Zlo[dd+0][mloc] = f2bf(zv.x - bf2f(h0));
        u16 h1 = f2bf(zv.y); Zhi[dd+1][mloc] = h1; Zlo[dd+1][mloc] = f2bf(zv.y - bf2f(h1));
        u16 h2 = f2bf(zv.z); Zhi[dd+2][mloc] = h2; Zlo[dd+2][mloc] = f2bf(zv.z - bf2f(h2));
        u16 h3 = f2bf(zv.w); Zhi[dd+3][mloc] = h3; Zlo[dd+3][mloc] = f2bf(zv.w - bf2f(h3));
      }
    }
    __syncthreads();
    #pragma unroll
    for (int kt = 0; kt < 4; ++kt){
      bf16x8 a  = *(const bf16x8*)&Pt[nh*32 + l32][kt*16 + h32*8];
      bf16x8 bh = *(const bf16x8*)&Zhi[dh*32 + l32][kt*16 + h32*8];
      bf16x8 bl = *(const bf16x8*)&Zlo[dh*32 + l32][kt*16 + h32*8];
      acch = mfma_bf16_32(a, bh, acch);
      accl = mfma_bf16_32(a, bl, accl);
    }
    __syncthreads();
  }
  #pragma unroll
  for (int g = 0; g < 16; ++g){
    const int row = (g&3) + 8*(g>>2) + 4*h32;
    Y[((size_t)b*2048 + n0 + nh*32 + row)*64 + dh*32 + l32] = acch[g] + accl[g];
  }
}

// ---------------------------------------------------------------------------
// K3: gate SAGC -> zs = z*state, rws = r. One block per node n.
// ---------------------------------------------------------------------------
__global__ void k_gate(const float* __restrict__ E, const float* __restrict__ gw, const float* __restrict__ gb,
                       const float* __restrict__ x, const float* __restrict__ state,
                       const float* __restrict__ c1x, const float* __restrict__ c1s,
                       float* __restrict__ zs, float* __restrict__ rws){
  __shared__ float Ew[16];
  __shared__ float bnv[128];
  __shared__ float Wn[2][66][64];
  __shared__ float xg4[4][2][66];
  const int t = threadIdx.x, n = blockIdx.x;
  if (t < 16) Ew[t] = E[n*16 + t];
  __syncthreads();
  if (t < 128){
    float a = 0.f;
    #pragma unroll
    for (int e=0;e<16;e++) a += Ew[e]*gb[e*128 + t];
    bnv[t] = a;
  }
  for (int half=0; half<2; ++half){
    for (int idx=t; idx<8448; idx+=256){
      int o = idx & 63, rest = idx>>6, i = rest % 66, k = rest / 66;
      float a = 0.f;
      #pragma unroll
      for (int e=0;e<16;e++) a += Ew[e]*gw[((e*2+k)*66 + i)*128 + half*64 + o];
      Wn[k][i][o] = a;
    }
    __syncthreads();
    for (int bb=0; bb<4; ++bb){
      for (int idx=t; idx<528; idx+=256){
        int bi = idx/132, rem = idx%132, k = rem/66, i = rem%66;
        int b = bb*4 + bi;
        float v;
        if (k==0) v = (i<2) ? x[((size_t)b*2048+n)*2 + i] : state[((size_t)b*2048+n)*64 + (i-2)];
        else      v = (i<2) ? c1x[((size_t)b*2048+n)*2 + i] : c1s[((size_t)b*2048+n)*64 + (i-2)];
        xg4[bi][k][i] = v;
      }
      __syncthreads();
      {
        int bi = t>>6, o = t&63, b = bb*4 + bi;
        float a = 0.f;
        #pragma unroll
        for (int k=0;k<2;k++)
          for (int i=0;i<66;i++) a += xg4[bi][k][i]*Wn[k][i][o];
        a += bnv[half*64 + o];
        float s = 1.f/(1.f + expf(-a));
        if (half==0) zs[((size_t)b*2048+n)*64 + o] = s*state[((size_t)b*2048+n)*64 + o];
        else         rws[((size_t)b*2048+n)*64 + o] = s;
      }
      __syncthreads();
    }
  }
}

// ---------------------------------------------------------------------------
// K3b: update SAGC -> hc -> h = r*state + (1-r)*hc.
// ---------------------------------------------------------------------------
__global__ void k_upd(const float* __restrict__ E, const float* __restrict__ uw, const float* __restrict__ ub,
                      const float* __restrict__ x, const float* __restrict__ state,
                      const float* __restrict__ zs, const float* __restrict__ c1x, const float* __restrict__ c2s,
                      const float* __restrict__ rws, float* __restrict__ h){
  __shared__ float Ew[16];
  __shared__ float bnu[64];
  __shared__ float Wn[2][66][64];
  __shared__ float xg4[4][2][66];
  const int t = threadIdx.x, n = blockIdx.x;
  if (t < 16) Ew[t] = E[n*16 + t];
  __syncthreads();
  if (t < 64){
    float a = 0.f;
    #pragma unroll
    for (int e=0;e<16;e++) a += Ew[e]*ub[e*64 + t];
    bnu[t] = a;
  }
  for (int idx=t; idx<8448; idx+=256){
    int o = idx & 63, rest = idx>>6, i = rest % 66, k = rest / 66;
    float a = 0.f;
    #pragma unroll
    for (int e=0;e<16;e++) a += Ew[e]*uw[((e*2+k)*66 + i)*64 + o];
    Wn[k][i][o] = a;
  }
  __syncthreads();
  for (int bb=0; bb<4; ++bb){
    for (int idx=t; idx<528; idx+=256){
      int bi = idx/132, rem = idx%132, k = rem/66, i = rem%66;
      int b = bb*4 + bi;
      float v;
      if (k==0) v = (i<2) ? x[((size_t)b*2048+n)*2 + i] : zs[((size_t)b*2048+n)*64 + (i-2)];
      else      v = (i<2) ? c1x[((size_t)b*2048+n)*2 + i] : c2s[((size_t)b*2048+n)*64 + (i-2)];
      xg4[bi][k][i] = v;
    }
    __syncthreads();
    {
      int bi = t>>6, o = t&63, b = bb*4 + bi;
      float a = 0.f;
      #pragma unroll
      for (int k=0;k<2;k++)
        for (int i=0;i<66;i++) a += xg4[bi][k][i]*Wn[k][i][o];
      float hc = tanhf(a + bnu[o]);
      float rv = rws[((size_t)b*2048+n)*64 + o];
      h[((size_t)b*2048+n)*64 + o] = rv*state[((size_t)b*2048+n)*64 + o] + (1.f - rv)*hc;
    }
    __syncthreads();
  }
}

// ---------------------------------------------------------------------------
// online-softmax step for one n-half: rescale running state, exp/pack the two
// logit tiles (kti=0,1), PV-accumulate. Shared ht frags across nh (caller).
// ---------------------------------------------------------------------------
static __device__ __forceinline__ void sm_step(f32x16& LK0, f32x16& LK1,
    f32x16& OA, f32x16& OB, float& mrun, float& srun,
    const u8* __restrict__ htb, int ktA, int ktB, int lane, int h32){
  const float LN256 = 5.545177444479562f;
  float cmax = LK0[0];
  #pragma unroll
  for (int g=1; g<16; ++g) cmax = fmaxf(cmax, LK0[g]);
  #pragma unroll
  for (int g=0; g<16; ++g) cmax = fmaxf(cmax, LK1[g]);
  cmax = fmaxf(cmax, __shfl_xor(cmax, 32));
  float mnew = fmaxf(mrun, 0.5f*cmax);
  float sc = __expf(mrun - mnew);
  srun *= sc;
  #pragma unroll
  for (int g=0; g<16; ++g){
    const int rowl = (g&3) + 8*(g>>2) + 4*h32;
    float fr = __shfl(sc, rowl);
    OA[g] *= fr; OB[g] *= fr;
  }
  float cs = 0.f;
  #pragma unroll
  for (int kti=0; kti<2; ++kti){
    const int kt = kti ? ktB : ktA;
    float p[16];
    #pragma unroll
    for (int g=0; g<16; ++g){
      float Lg = kti ? LK1[g] : LK0[g];
      p[g] = __expf(0.5f*Lg - mnew + LN256);   // 256-scaled
      cs += p[g];
    }
    u32 qA = pk4_fp8(p[0],p[1],p[2],p[3]);
    u32 qB = pk4_fp8(p[4],p[5],p[6],p[7]);
    u32 qC = pk4_fp8(p[8],p[9],p[10],p[11]);
    u32 qD = pk4_fp8(p[12],p[13],p[14],p[15]);
    u32 xA = __shfl_xor(qA,32), xB = __shfl_xor(qB,32);
    u32 xC = __shfl_xor(qC,32), xD = __shfl_xor(qD,32);
    long pf0 = h32 ? mklong(xB,qB) : mklong(qA,xA);
    long pf1 = h32 ? mklong(xD,qD) : mklong(qC,xC);
    long h00 = *(const long*)(htb + (size_t)((kt*2+0)*2 + 0)*512 + lane*8);
    long h01 = *(const long*)(htb + (size_t)((kt*2+0)*2 + 1)*512 + lane*8);
    long h10 = *(const long*)(htb + (size_t)((kt*2+1)*2 + 0)*512 + lane*8);
    long h11 = *(const long*)(htb + (size_t)((kt*2+1)*2 + 1)*512 + lane*8);
    OA = mfma_fp8_32(pf0, h00, OA);
    OB = mfma_fp8_32(pf0, h01, OB);
    OA = mfma_fp8_32(pf1, h10, OA);
    OB = mfma_fp8_32(pf1, h11, OB);
  }
  cs += __shfl_xor(cs, 32);
  srun += cs;
  mrun = mnew;
}

// ---------------------------------------------------------------------------
// K5: fused degrees — R14: wave = ALL 64 n-rows x 256 k-cols (kq = w).
// R13 read W twice per block (both nh-waves of a kq pair streamed identical
// W): 17.2 MB/CU L1-fill = 112us vs 130us MFMA — the hidden serializer.
// Now the 8 waves' k-slices tile W exactly once: 4.3 MB/block, 8.6 MB/CU
// (~56us fill < MFMA floor). Per si (2 kt): same 16-MFMA pt-loop shape
// (S-frags shared across kt, W-frags shared across nh); softmax/PV per nh;
// LSE merge widens to 8 partials (scratch 8x64x64 f32 = 128 KB in dead S).
// Math identical to R13 => absmax unchanged. p0 rotation + setprio kept.
// ---------------------------------------------------------------------------
#define SROW8 2056

__global__ void __launch_bounds__(512,2) k_deg(
    const u32* __restrict__ mbits, const u16* __restrict__ hb16,
    const u8* __restrict__ W8,
    const u8* __restrict__ ht8p, const u16* __restrict__ hfm,
    const float* __restrict__ hf32, const float* __restrict__ oc_in,
    float* __restrict__ outp, int fin){
  extern __shared__ u8 S[];
  __shared__ float maxw[64][8];
  __shared__ float sumw[64][8];
  __shared__ float sgl_lds[64];
  const int t = threadIdx.x;
  const int w = t >> 6, lane = t & 63, lc = lane & 15, q = lane >> 4;
  const int l32 = lane & 31, h32 = lane >> 5;
  const int id = blockIdx.x;
  const int b = id >> 5, n0 = (id & 31) * 64;
  const int p0 = (id >> 3) & 31;          // per-CU-within-XCD rotation offset
  const u32* mrow0 = mbits + (size_t)(n0 >> 5)*2048;
  const u32* mrow1 = mrow0 + 2048;
  const u16* hbb = hb16 + (size_t)b*2048*64;
  const u16* hfb = hfm + (size_t)b*131072;
  const u8* htb = ht8p + (size_t)b*131072;

  // ---- phase 1: S[r][m] = fp8( (bit ? h_n.h_m : 0) / 8 ), 64 rows ----
  {
    const int c0 = p0 & 15;
    bf16x8 A[4][2];
    #pragma unroll
    for (int rt=0; rt<4; ++rt)
      #pragma unroll
      for (int ks=0; ks<2; ++ks)
        A[rt][ks] = *(const bf16x8*)&hbb[(size_t)(n0 + rt*16 + lc)*64 + ks*32 + q*8];
    int ctg0 = w*16 + c0;
    bf16x8 B0c = *(const bf16x8*)(hfb + (size_t)ctg0*512 + lane*8);
    bf16x8 B1c = *(const bf16x8*)(hfb + 65536 + (size_t)ctg0*512 + lane*8);
    u32 m0c = mrow0[ctg0*16 + lc], m1c = mrow1[ctg0*16 + lc];
    #pragma unroll 1
    for (int ct=0; ct<16; ++ct){
      const int ctg  = w*16 + ((ct + c0) & 15);
      const int ctgn = w*16 + ((ct + 1 + c0) & 15);
      bf16x8 B0n = *(const bf16x8*)(hfb + (size_t)ctgn*512 + lane*8);
      bf16x8 B1n = *(const bf16x8*)(hfb + 65536 + (size_t)ctgn*512 + lane*8);
      u32 m0n = mrow0[ctgn*16 + lc], m1n = mrow1[ctgn*16 + lc];
      const int mcol = ctg*16 + lc;
      f32x4 a[4];
      #pragma unroll
      for (int rt=0; rt<4; ++rt){
        a[rt] = (f32x4){0.f,0.f,0.f,0.f};
        a[rt] = mfma_bf16(A[rt][0], B0c, a[rt]);
        a[rt] = mfma_bf16(A[rt][1], B1c, a[rt]);
      }
      #pragma unroll
      for (int rt=0; rt<4; ++rt){
        const u32 mw = (rt < 2) ? m0c : m1c;
        #pragma unroll
        for (int i=0;i<4;i++){
          const int row = rt*16 + q*4 + i;
          float v = ((mw >> (row & 31)) & 1u) ? a[rt][i]*0.125f : 0.f;
          S[row*SROW8 + mcol] = f2fp8(v);
        }
      }
      B0c = B0n; B1c = B1n; m0c = m0n; m1c = m1n;
    }
  }
  __syncthreads();

  // ---- fused phases 2+3+4: wave w owns k-cols [w*256,(w+1)*256), all 64 n ----
  const u8* sb0 = S + (size_t)l32*SROW8 + h32*8;          // nh0 rows
  const u8* sb1 = S + (size_t)(32 + l32)*SROW8 + h32*8;   // nh1 rows
  const u8* wl = W8 + lane*16;
  f32x16 oA0 = (f32x16)(0.f), oA1 = (f32x16)(0.f);        // nh0: dt0, dt1
  f32x16 oB0 = (f32x16)(0.f), oB1 = (f32x16)(0.f);        // nh1
  float mrun0 = -1e30f, srun0 = 0.f, mrun1 = -1e30f, srun1 = 0.f;
  #pragma unroll 1
  for (int si = 0; si < 4; ++si){
    const int ktA = w*8 + si*2, ktB = ktA + 1;
    f32x16 L00 = (f32x16)(0.f), L01 = (f32x16)(0.f);      // kti0: nh0, nh1
    f32x16 L10 = (f32x16)(0.f), L11 = (f32x16)(0.f);      // kti1
    uint4 wv0, wv1, wv2, wv3;
    {
      const int pt0 = p0;
      wv0 = *(const uint4*)(wl + (size_t)((pt0*64 + ktA)*2 + 0)*1024);
      wv1 = *(const uint4*)(wl + (size_t)((pt0*64 + ktA)*2 + 1)*1024);
      wv2 = *(const uint4*)(wl + (size_t)((pt0*64 + ktB)*2 + 0)*1024);
      wv3 = *(const uint4*)(wl + (size_t)((pt0*64 + ktB)*2 + 1)*1024);
    }
    __builtin_amdgcn_s_setprio(1);
    #pragma unroll 1
    for (int pti = 0; pti < 32; ++pti){
      const int pt  = (pti + p0) & 31;
      const int ptn = (pti + 1 + p0) & 31;
      long b00 = *(const long*)(sb0 + pt*64 +  0);
      long b01 = *(const long*)(sb0 + pt*64 + 16);
      long b02 = *(const long*)(sb0 + pt*64 + 32);
      long b03 = *(const long*)(sb0 + pt*64 + 48);
      long b10 = *(const long*)(sb1 + pt*64 +  0);
      long b11 = *(const long*)(sb1 + pt*64 + 16);
      long b12 = *(const long*)(sb1 + pt*64 + 32);
      long b13 = *(const long*)(sb1 + pt*64 + 48);
      uint4 wn0 = *(const uint4*)(wl + (size_t)((ptn*64 + ktA)*2 + 0)*1024);
      uint4 wn1 = *(const uint4*)(wl + (size_t)((ptn*64 + ktA)*2 + 1)*1024);
      uint4 wn2 = *(const uint4*)(wl + (size_t)((ptn*64 + ktB)*2 + 0)*1024);
      uint4 wn3 = *(const uint4*)(wl + (size_t)((ptn*64 + ktB)*2 + 1)*1024);
      L00 = mfma_fp8_32(lo64(wv0), b00, L00);
      L01 = mfma_fp8_32(lo64(wv0), b10, L01);
      L10 = mfma_fp8_32(lo64(wv2), b00, L10);
      L11 = mfma_fp8_32(lo64(wv2), b10, L11);
      L00 = mfma_fp8_32(hi64(wv0), b01, L00);
      L01 = mfma_fp8_32(hi64(wv0), b11, L01);
      L10 = mfma_fp8_32(hi64(wv2), b01, L10);
      L11 = mfma_fp8_32(hi64(wv2), b11, L11);
      L00 = mfma_fp8_32(lo64(wv1), b02, L00);
      L01 = mfma_fp8_32(lo64(wv1), b12, L01);
      L10 = mfma_fp8_32(lo64(wv3), b02, L10);
      L11 = mfma_fp8_32(lo64(wv3), b12, L11);
      L00 = mfma_fp8_32(hi64(wv1), b03, L00);
      L01 = mfma_fp8_32(hi64(wv1), b13, L01);
      L10 = mfma_fp8_32(hi64(wv3), b03, L10);
      L11 = mfma_fp8_32(hi64(wv3), b13, L11);
      wv0 = wn0; wv1 = wn1; wv2 = wn2; wv3 = wn3;
    }
    __builtin_amdgcn_s_setprio(0);
    sm_step(L00, L10, oA0, oA1, mrun0, srun0, htb, ktA, ktB, lane, h32);
    sm_step(L01, L11, oB0, oB1, mrun1, srun1, htb, ktA, ktB, lane, h32);
  }

  // ---- merge: log-sum-exp combine of 8 k-slices ----
  if (h32 == 0){
    maxw[l32][w] = mrun0;      sumw[l32][w] = srun0;
    maxw[32 + l32][w] = mrun1; sumw[32 + l32][w] = srun1;
  }
  __syncthreads();                        // all S reads done; max/sum visible
  float* scr = (float*)S;
  {
    float m_g0 = maxw[l32][0];
    #pragma unroll
    for (int j=1;j<8;j++) m_g0 = fmaxf(m_g0, maxw[l32][j]);
    float s_g0 = 0.f;
    #pragma unroll
    for (int j=0;j<8;j++) s_g0 += sumw[l32][j]*__expf(maxw[l32][j]-m_g0);
    float m_g1 = maxw[32+l32][0];
    #pragma unroll
    for (int j=1;j<8;j++) m_g1 = fmaxf(m_g1, maxw[32+l32][j]);
    float s_g1 = 0.f;
    #pragma unroll
    for (int j=0;j<8;j++) s_g1 += sumw[32+l32][j]*__expf(maxw[32+l32][j]-m_g1);
    if (w == 0 && h32 == 0){
      sgl_lds[l32] = s_g0;
      sgl_lds[32 + l32] = s_g1;
    }
    float f0 = __expf(mrun0 - m_g0);
    float f1 = __expf(mrun1 - m_g1);
    #pragma unroll
    for (int g=0; g<16; ++g){
      const int rowl = (g&3) + 8*(g>>2) + 4*h32;
      float fr0 = __shfl(f0, rowl);
      float fr1 = __shfl(f1, rowl);
      scr[((size_t)w*64 + rowl)*64 + l32]           = oA0[g]*fr0;
      scr[((size_t)w*64 + rowl)*64 + 32 + l32]      = oA1[g]*fr0;
      scr[((size_t)w*64 + 32 + rowl)*64 + l32]      = oB0[g]*fr1;
      scr[((size_t)w*64 + 32 + rowl)*64 + 32 + l32] = oB1[g]*fr1;
    }
  }
  __syncthreads();

  // ---- reduce 8 partials + epilogue ----
  {
    const int n_g = t >> 3, d0 = (t & 7)*8;
    const float sdiv = sgl_lds[n_g];
    float* op = outp + (size_t)b*2048*64;
    const float* hp = hf32 + (size_t)b*2048*64;
    const float* cp = oc_in + (size_t)b*2048*64;
    #pragma unroll
    for (int j=0;j<8;j++){
      const int d = d0 + j;
      float v = 0.f;
      #pragma unroll
      for (int qq=0; qq<8; ++qq)
        v += scr[((size_t)qq*64 + n_g)*64 + d];
      v /= sdiv;
      size_t idx = (size_t)(n0 + n_g)*64 + d;
      if (fin) v = 0.8f*hp[idx] - 0.1f*cp[idx] + 0.1f*v;
      op[idx] = v;
    }
  }
}

// ---------------------------------------------------------------------------
extern "C" void kernel_launch(void* const* d_in, const int* in_sizes, int n_in,
                              void* d_out, int out_size, void* d_ws, size_t ws_size,
                              hipStream_t stream) {
  const float* x     = (const float*)d_in[0];
  const float* state = (const float*)d_in[1];
  const float* E     = (const float*)d_in[2];
  const float* Wc    = (const float*)d_in[3];
  const float* Wd    = (const float*)d_in[4];
  const float* gw    = (const float*)d_in[5];
  const float* gb    = (const float*)d_in[6];
  const float* uw    = (const float*)d_in[7];
  const float* ub    = (const float*)d_in[8];

  // workspace layout (bytes). Total 73,662,464 B = 70.2 MB.
  char* base = (char*)d_ws;
  u16*   P    = (u16*)(base + 0);           //  8,388,608  (dead after 2nd k_conv)
  u32*   mp2  = (u32*)(base + 0);           //    524,288  (aliases P; written after P dead)
  u32*   mn2  = (u32*)(base + 524288);      //    524,288  (aliases P)
  u8*    msk  = (u8*) (base + 8388608);     //  4,194,304
  u8*    Wc8  = (u8*) (base + 12582912);    //  4,194,304
  u8*    Wd8  = (u8*) (base + 16777216);    //  4,194,304
  u16*   hb16 = (u16*)(base + 20971520);    //  4,194,304
  u8*    ht8p = (u8*) (base + 25165824);    //  2,097,152
  u16*   hfm  = (u16*)(base + 27262976);    //  4,194,304
  float* c1x  = (float*)(base + 31457280);  //    262,144
  float* c1s  = (float*)(base + 31719424);  //  8,388,608
  float* zs   = (float*)(base + 40108032);  //  8,388,608
  float* rws  = (float*)(base + 48496640);  //  8,388,608
  float* c2s  = (float*)(base + 56885248);  //  8,388,608
  float* h    = (float*)(base + 65273856);  //  8,388,608
  float* oc   = c1s;                        // dead after k_gate
  float* od   = c2s;                        // dead after k_upd (unused placeholder)

  k_w8<<<dim3(32,32,2), 256, 0, stream>>>(Wc, Wd, Wc8, Wd8);
  k_P<<<2048, 256, 0, stream>>>(E, P, msk);
  k_c1x<<<dim3(32,16), 128, 0, stream>>>(P, x, c1x);
  k_conv<<<dim3(32,16), 256, 0, stream>>>(P, state, c1s);
  k_gate<<<2048, 256, 0, stream>>>(E, gw, gb, x, state, c1x, c1s, zs, rws);
  k_conv<<<dim3(32,16), 256, 0, stream>>>(P, zs, c2s);
  k_upd<<<2048, 256, 0, stream>>>(E, uw, ub, x, state, zs, c1x, c2s, rws, h);
  k_hcvt<<<dim3(32,16), 256, 0, stream>>>(h, hb16, ht8p, hfm);
  k_mbits<<<dim3(2048,8), 256, 0, stream>>>(msk, mp2, mn2);   // P dead by now

  const int deg_lds = 64*SROW8;   // 131,584 B dynamic (+~4.3 KB static)
  hipFuncSetAttribute((const void*)k_deg, hipFuncAttributeMaxDynamicSharedMemorySize, deg_lds);
  // dispatch 1: connect mask — only Wc8 hot in every XCD L2
  k_deg<<<512, 512, deg_lds, stream>>>(mp2, hb16, Wc8, ht8p, hfm, h, h, oc, 0);
  // dispatch 2: disconnect mask — only Wd8 hot; fused final epilogue -> d_out
  k_deg<<<512, 512, deg_lds, stream>>>(mn2, hb16, Wd8, ht8p, hfm, h, oc, (float*)d_out, 1);
}

// Round 8
// 988.418 us; speedup vs baseline: 1.9114x; 1.0406x over previous
//
#include <hip/hip_runtime.h>
#include <hip/hip_bf16.h>

typedef unsigned short u16;
typedef unsigned int   u32;
typedef unsigned char  u8;

typedef __attribute__((ext_vector_type(8))) short bf16x8;
typedef __attribute__((ext_vector_type(4))) float f32x4;
typedef __attribute__((ext_vector_type(16))) float f32x16;

static __device__ __forceinline__ float bf2f(u16 u){ return __uint_as_float(((u32)u)<<16); }
static __device__ __forceinline__ u16 f2bf(float f){
  u32 u = __float_as_uint(f);
  u32 r = (u + 0x7fff + ((u>>16)&1)) >> 16;   // RNE; inputs finite
  return (u16)r;
}

// fp8 e4m3 (OCP) helpers — HW cvt, saturating via pre-clamp
static __device__ __forceinline__ u8 f2fp8(float v){
  v = fminf(440.f, fmaxf(-440.f, v));
  return (u8)(__builtin_amdgcn_cvt_pk_fp8_f32(v, 0.f, 0, false) & 0xff);
}
static __device__ __forceinline__ u32 pk4_fp8(float a, float b, float c, float d){
  int w = __builtin_amdgcn_cvt_pk_fp8_f32(a, b, 0, false);
  w = __builtin_amdgcn_cvt_pk_fp8_f32(c, d, w, true);
  return (u32)w;
}

static __device__ __forceinline__ f32x4 mfma_bf16(bf16x8 a, bf16x8 b, f32x4 c){
  return __builtin_amdgcn_mfma_f32_16x16x32_bf16(a, b, c, 0, 0, 0);
}
static __device__ __forceinline__ f32x16 mfma_bf16_32(bf16x8 a, bf16x8 b, f32x16 c){
  return __builtin_amdgcn_mfma_f32_32x32x16_bf16(a, b, c, 0, 0, 0);
}
static __device__ __forceinline__ f32x16 mfma_fp8_32(long a, long b, f32x16 c){
  return __builtin_amdgcn_mfma_f32_32x32x16_fp8_fp8(a, b, c, 0, 0, 0);
}
static __device__ __forceinline__ long lo64(uint4 v){ return (long)(((unsigned long long)v.y<<32) | v.x); }
static __device__ __forceinline__ long hi64(uint4 v){ return (long)(((unsigned long long)v.w<<32) | v.z); }
static __device__ __forceinline__ long mklong(u32 lo, u32 hi){ return (long)(((unsigned long long)hi<<32) | lo); }

// ---------------------------------------------------------------------------
// K-w8: W f32 [m][k] -> fp8 packed, 1KB block per (pt=m/64, kt=k/32, mcp):
//   byte at lane*16 + sel*8 + j = W[pt*64 + (mcp*2+sel)*16 + (lane>>5)*8 + j][kt*32 + (lane&31)]
// Serves BOTH as 32x32x16 B-frag (m x k) and as A-frag of W^T (k x m).
// grid (32,32,2), block 256.
// ---------------------------------------------------------------------------
__global__ void k_w8(const float* __restrict__ Wc, const float* __restrict__ Wd,
                     u8* __restrict__ Wc8, u8* __restrict__ Wd8){
  __shared__ float tile[64][65];
  const float* src = blockIdx.z ? Wd : Wc;
  u8* dst = blockIdx.z ? Wd8 : Wc8;
  const int m0 = blockIdx.x*64, k0 = blockIdx.y*64;
  const int t = threadIdx.x, r = t & 63, cc = t >> 6;
  #pragma unroll
  for (int j=0;j<4;j++){
    float4 v = *(const float4*)&src[(size_t)(m0+r)*2048 + k0 + cc*16 + j*4];
    tile[r][cc*16+j*4+0]=v.x; tile[r][cc*16+j*4+1]=v.y;
    tile[r][cc*16+j*4+2]=v.z; tile[r][cc*16+j*4+3]=v.w;
  }
  __syncthreads();
  const int lane = t & 63, sub = t >> 6;     // sub 0..3
  const int kth = sub & 1, mcp = sub >> 1;
  const int kl = kth*32 + (lane & 31);       // k within 64-tile
  const int ml = mcp*32 + (lane >> 5)*8;     // m base within 64-tile
  u32 b0 = pk4_fp8(16.f*tile[ml+ 0][kl], 16.f*tile[ml+ 1][kl], 16.f*tile[ml+ 2][kl], 16.f*tile[ml+ 3][kl]);
  u32 b1 = pk4_fp8(16.f*tile[ml+ 4][kl], 16.f*tile[ml+ 5][kl], 16.f*tile[ml+ 6][kl], 16.f*tile[ml+ 7][kl]);
  u32 b2 = pk4_fp8(16.f*tile[ml+16][kl], 16.f*tile[ml+17][kl], 16.f*tile[ml+18][kl], 16.f*tile[ml+19][kl]);
  u32 b3 = pk4_fp8(16.f*tile[ml+20][kl], 16.f*tile[ml+21][kl], 16.f*tile[ml+22][kl], 16.f*tile[ml+23][kl]);
  const int pt = m0 >> 6, kt = (k0 >> 5) + kth;
  u8* dbase = dst + (size_t)((pt*64 + kt)*2 + mcp)*1024 + lane*16;
  *(uint4*)dbase = make_uint4(b0, b1, b2, b3);
}

// ---------------------------------------------------------------------------
// K-hcvt: h f32 [b][m][64] -> hb16 (bf16 row-major), hfm (bf16 frag-major B for
// phase 1), ht8p (fp8 32x32x16-B frags: addr (k16*2 + dt)*512 + lane*8 + j ->
// h[k16*16 + (lane>>5)*8 + j][dt*32 + (lane&31)]). grid (32,16), block 256.
// ---------------------------------------------------------------------------
__global__ void k_hcvt(const float* __restrict__ h, u16* __restrict__ hb16,
                       u8* __restrict__ ht8p, u16* __restrict__ hfm){
  __shared__ float tile[64][65];
  const int k0 = blockIdx.x*64, b = blockIdx.y;
  const int t = threadIdx.x, r = t & 63, cc = t >> 6;
  const float* src = h + ((size_t)b*2048 + k0)*64;
  u32 hw[8];
  #pragma unroll
  for (int j=0;j<4;j++){
    float4 v = *(const float4*)&src[(size_t)r*64 + cc*16 + j*4];
    tile[r][cc*16+j*4+0]=v.x; tile[r][cc*16+j*4+1]=v.y;
    tile[r][cc*16+j*4+2]=v.z; tile[r][cc*16+j*4+3]=v.w;
    hw[2*j]   = (u32)f2bf(v.x) | ((u32)f2bf(v.y)<<16);
    hw[2*j+1] = (u32)f2bf(v.z) | ((u32)f2bf(v.w)<<16);
  }
  u16* hp = hb16 + (((size_t)b*2048 + k0 + r)*64 + cc*16);
  *(uint4*)hp     = make_uint4(hw[0],hw[1],hw[2],hw[3]);
  *(uint4*)(hp+8) = make_uint4(hw[4],hw[5],hw[6],hw[7]);
  __syncthreads();
  {
    // ht8p: 32x32x16 B-frag layout for out-MFMA (k x d)
    const int lane = t & 63, sub = cc;          // sub = local k16 index 0..3
    const int k16 = (k0 >> 4) + sub;
    const int lr = sub*16 + ((lane >> 5) << 3); // local row in tile
    const int d0 = lane & 31;
    #pragma unroll
    for (int dt=0; dt<2; ++dt){
      const int d = dt*32 + d0;
      u32 w0 = pk4_fp8(tile[lr+0][d], tile[lr+1][d], tile[lr+2][d], tile[lr+3][d]);
      u32 w1 = pk4_fp8(tile[lr+4][d], tile[lr+5][d], tile[lr+6][d], tile[lr+7][d]);
      *(uint2*)(ht8p + (size_t)b*131072 + (size_t)(k16*2 + dt)*512 + lane*8) = make_uint2(w0, w1);
    }
  }
  {
    const int col = k0 + r, ks = cc >> 1, q0 = (cc & 1)*2;
    const int ctg = col >> 4, lcv = col & 15;
    u16* fbase = hfm + (size_t)b*131072 + (size_t)ks*65536 + ((size_t)ctg*64)*8;
    #pragma unroll
    for (int qq=0; qq<2; ++qq){
      int q = q0 + qq;
      u32 p0 = (u32)f2bf(tile[r][ks*32+q*8+0]) | ((u32)f2bf(tile[r][ks*32+q*8+1])<<16);
      u32 p1 = (u32)f2bf(tile[r][ks*32+q*8+2]) | ((u32)f2bf(tile[r][ks*32+q*8+3])<<16);
      u32 p2 = (u32)f2bf(tile[r][ks*32+q*8+4]) | ((u32)f2bf(tile[r][ks*32+q*8+5])<<16);
      u32 p3 = (u32)f2bf(tile[r][ks*32+q*8+6]) | ((u32)f2bf(tile[r][ks*32+q*8+7])<<16);
      *(uint4*)(fbase + (size_t)(q*16 + lcv)*8) = make_uint4(p0,p1,p2,p3);
    }
  }
}

// ---------------------------------------------------------------------------
// K1: row n of A = E E^T. sign-mask (1 pos, 2 neg) + P=softmax(relu) bf16.
// R15: float4 E loads (16 scalar -> 4 vector loads per dot).
// ---------------------------------------------------------------------------
__global__ void k_P(const float* __restrict__ E, u16* __restrict__ P, u8* __restrict__ msk){
  __shared__ float Ew[16];
  __shared__ float arow[2048];
  __shared__ float red[4];
  const int t = threadIdx.x, n = blockIdx.x;
  if (t < 16) Ew[t] = E[n*16 + t];
  __syncthreads();
  float lmax = 0.f;
  for (int i=0;i<8;i++){
    int m = t + 256*i;
    const float4* ep = (const float4*)(E + m*16);
    float4 e0 = ep[0], e1 = ep[1], e2 = ep[2], e3 = ep[3];
    float dot = e0.x*Ew[0] + e0.y*Ew[1] + e0.z*Ew[2] + e0.w*Ew[3]
              + e1.x*Ew[4] + e1.y*Ew[5] + e1.z*Ew[6] + e1.w*Ew[7]
              + e2.x*Ew[8] + e2.y*Ew[9] + e2.z*Ew[10] + e2.w*Ew[11]
              + e3.x*Ew[12] + e3.y*Ew[13] + e3.z*Ew[14] + e3.w*Ew[15];
    msk[n*2048 + m] = dot > 0.f ? (u8)1 : (dot < 0.f ? (u8)2 : (u8)0);
    float ar = fmaxf(dot, 0.f);
    arow[m] = ar;
    lmax = fmaxf(lmax, ar);
  }
  for (int o=1;o<64;o<<=1) lmax = fmaxf(lmax, __shfl_xor(lmax, o));
  if ((t&63)==0) red[t>>6] = lmax;
  __syncthreads();
  float gmax = fmaxf(fmaxf(red[0],red[1]), fmaxf(red[2],red[3]));
  __syncthreads();
  float lsum = 0.f;
  for (int i=0;i<8;i++){
    int m = t + 256*i;
    float e = expf(arow[m] - gmax);
    arow[m] = e;
    lsum += e;
  }
  for (int o=1;o<64;o<<=1) lsum += __shfl_xor(lsum, o);
  if ((t&63)==0) red[t>>6] = lsum;
  __syncthreads();
  float inv = 1.f/(red[0]+red[1]+red[2]+red[3]);
  for (int i=0;i<8;i++){
    int m = t + 256*i;
    P[n*2048 + m] = f2bf(arow[m]*inv);
  }
}

// ---------------------------------------------------------------------------
// K-mbits (R15 rewrite): msk u8 [n][m] -> transposed bitmaps mp2/mn2.
// LDS-tiled: block = (64 m) x (256 n). Stage 256x64 tile with aligned uint2
// row loads (stride 72), build words from broadcast-friendly column reads,
// coalesced u32 stores. L2 line traffic ~0.5 GB -> ~8 MB vs old 16K scalar
// blocks. grid (32, 8), block 256.
// ---------------------------------------------------------------------------
__global__ void k_mbits(const u8* __restrict__ msk, u32* __restrict__ mp2, u32* __restrict__ mn2){
  __shared__ u8 tile[256][72];
  const int m0 = blockIdx.x*64, n0 = blockIdx.y*256;
  const int t = threadIdx.x;
  {
    const u8* src = msk + (size_t)(n0 + t)*2048 + m0;
    #pragma unroll
    for (int j=0;j<8;j++)
      *(uint2*)&tile[t][j*8] = *(const uint2*)(src + j*8);
  }
  __syncthreads();
  const int m = t & 63, g = t >> 6;
  #pragma unroll
  for (int jj=0; jj<2; ++jj){
    const int j = g + jj*4;                 // n-word 0..7 within tile
    u32 bp = 0, bn = 0;
    #pragma unroll
    for (int i=0;i<32;++i){
      u8 v = tile[j*32 + i][m];
      bp |= (u32)(v == (u8)1) << i;
      bn |= (u32)(v == (u8)2) << i;
    }
    const size_t wi = (size_t)((n0 >> 5) + j)*2048 + m0 + m;
    mp2[wi] = bp;
    mn2[wi] = bn;
  }
}

// ---------------------------------------------------------------------------
// K2 (R15): Y[b,n,d] = sum_m P[n,m] * Z[b,m,d] via bf16 MFMA with
// error-compensated split Z ~= Zhi + Zlo. 64x64 tile, 4 waves = (nh, dh).
// withx=1 additionally computes c1x[b,n,c] = sum_m P[n,m]*x[b,m,c] from the
// staged P tile (replaces the old scalar k_c1x kernel): 64x2 x-tile staged
// per mc, 32 FMA/thread hidden under the MFMAs, pairwise shfl reduce.
// grid (32,16), block 256.
// ---------------------------------------------------------------------------
__global__ void k_conv(const u16* __restrict__ P, const float* __restrict__ Z, float* __restrict__ Y,
                       const float* __restrict__ x, float* __restrict__ c1x, int withx){
  __shared__ u16 Pt[64][68];
  __shared__ u16 Zhi[64][68];
  __shared__ u16 Zlo[64][68];
  __shared__ float xt[64][2];
  const int t = threadIdx.x;
  const int w = t >> 6, lane = t & 63, l32 = lane & 31, h32 = lane >> 5;
  const int nh = w & 1, dh = w >> 1;
  const int n0 = blockIdx.x*64, b = blockIdx.y;
  const int mloc = t & 63, grp = t >> 6;
  f32x16 acch = (f32x16)(0.f), accl = (f32x16)(0.f);
  float xacc = 0.f;
  const int xnl = t >> 2, xc = (t >> 1) & 1, xmh = t & 1;
  for (int mc = 0; mc < 32; ++mc){
    const int m0 = mc*64;
    {
      const u16* pp = P + (size_t)(n0 + mloc)*2048 + m0 + grp*16;
      uint4 v0 = *(const uint4*)pp;
      uint4 v1 = *(const uint4*)(pp + 8);
      *(uint4*)&Pt[mloc][grp*16]     = v0;
      *(uint4*)&Pt[mloc][grp*16 + 8] = v1;
      const float* zp = Z + ((size_t)b*2048 + m0 + mloc)*64 + grp*16;
      #pragma unroll
      for (int jj = 0; jj < 4; ++jj){
        float4 zv = *(const float4*)(zp + jj*4);
        const int dd = grp*16 + jj*4;
        u16 h0 = f2bf(zv.x); Zhi[dd+0][mloc] = h0; Zlo[dd+0][mloc] = f2bf(zv.x - bf2f(h0));
        u16 h1 = f2bf(zv.y); Zhi[dd+1][mloc] = h1; Zlo[dd+1][mloc] = f2bf(zv.y - bf2f(h1));
        u16 h2 = f2bf(zv.z); Zhi[dd+2][mloc] = h2; Zlo[dd+2][mloc] = f2bf(zv.z - bf2f(h2));
        u16 h3 = f2bf(zv.w); Zhi[dd+3][mloc] = h3; Zlo[dd+3][mloc] = f2bf(zv.w - bf2f(h3));
      }
      if (withx && t < 128)
        xt[t>>1][t&1] = x[((size_t)b*2048 + m0 + (t>>1))*2 + (t&1)];
    }
    __syncthreads();
    #pragma unroll
    for (int kt = 0; kt < 4; ++kt){
      bf16x8 a  = *(const bf16x8*)&Pt[nh*32 + l32][kt*16 + h32*8];
      bf16x8 bh = *(const bf16x8*)&Zhi[dh*32 + l32][kt*16 + h32*8];
      bf16x8 bl = *(const bf16x8*)&Zlo[dh*32 + l32][kt*16 + h32*8];
      acch = mfma_bf16_32(a, bh, acch);
      accl = mfma_bf16_32(a, bl, accl);
    }
    if (withx){
      #pragma unroll
      for (int mi = 0; mi < 32; ++mi){
        const int ml = xmh*32 + mi;
        xacc += bf2f(Pt[xnl][ml])*xt[ml][xc];
      }
    }
    __syncthreads();
  }
  #pragma unroll
  for (int g = 0; g < 16; ++g){
    const int row = (g&3) + 8*(g>>2) + 4*h32;
    Y[((size_t)b*2048 + n0 + nh*32 + row)*64 + dh*32 + l32] = acch[g] + accl[g];
  }
  if (withx){
    float o = xacc + __shfl_xor(xacc, 1);
    if (xmh == 0)
      c1x[((size_t)b*2048 + n0 + xnl)*2 + xc] = o;
  }
}

// ---------------------------------------------------------------------------
// K3: gate SAGC -> zs = z*state, rws = r. One block per node n.
// ---------------------------------------------------------------------------
__global__ void k_gate(const float* __restrict__ E, const float* __restrict__ gw, const float* __restrict__ gb,
                       const float* __restrict__ x, const float* __restrict__ state,
                       const float* __restrict__ c1x, const float* __restrict__ c1s,
                       float* __restrict__ zs, float* __restrict__ rws){
  __shared__ float Ew[16];
  __shared__ float bnv[128];
  __shared__ float Wn[2][66][64];
  __shared__ float xg4[4][2][66];
  const int t = threadIdx.x, n = blockIdx.x;
  if (t < 16) Ew[t] = E[n*16 + t];
  __syncthreads();
  if (t < 128){
    float a = 0.f;
    #pragma unroll
    for (int e=0;e<16;e++) a += Ew[e]*gb[e*128 + t];
    bnv[t] = a;
  }
  for (int half=0; half<2; ++half){
    for (int idx=t; idx<8448; idx+=256){
      int o = idx & 63, rest = idx>>6, i = rest % 66, k = rest / 66;
      float a = 0.f;
      #pragma unroll
      for (int e=0;e<16;e++) a += Ew[e]*gw[((e*2+k)*66 + i)*128 + half*64 + o];
      Wn[k][i][o] = a;
    }
    __syncthreads();
    for (int bb=0; bb<4; ++bb){
      for (int idx=t; idx<528; idx+=256){
        int bi = idx/132, rem = idx%132, k = rem/66, i = rem%66;
        int b = bb*4 + bi;
        float v;
        if (k==0) v = (i<2) ? x[((size_t)b*2048+n)*2 + i] : state[((size_t)b*2048+n)*64 + (i-2)];
        else      v = (i<2) ? c1x[((size_t)b*2048+n)*2 + i] : c1s[((size_t)b*2048+n)*64 + (i-2)];
        xg4[bi][k][i] = v;
      }
      __syncthreads();
      {
        int bi = t>>6, o = t&63, b = bb*4 + bi;
        float a = 0.f;
        #pragma unroll
        for (int k=0;k<2;k++)
          for (int i=0;i<66;i++) a += xg4[bi][k][i]*Wn[k][i][o];
        a += bnv[half*64 + o];
        float s = 1.f/(1.f + expf(-a));
        if (half==0) zs[((size_t)b*2048+n)*64 + o] = s*state[((size_t)b*2048+n)*64 + o];
        else         rws[((size_t)b*2048+n)*64 + o] = s;
      }
      __syncthreads();
    }
  }
}

// ---------------------------------------------------------------------------
// K3b: update SAGC -> hc -> h = r*state + (1-r)*hc.
// ---------------------------------------------------------------------------
__global__ void k_upd(const float* __restrict__ E, const float* __restrict__ uw, const float* __restrict__ ub,
                      const float* __restrict__ x, const float* __restrict__ state,
                      const float* __restrict__ zs, const float* __restrict__ c1x, const float* __restrict__ c2s,
                      const float* __restrict__ rws, float* __restrict__ h){
  __shared__ float Ew[16];
  __shared__ float bnu[64];
  __shared__ float Wn[2][66][64];
  __shared__ float xg4[4][2][66];
  const int t = threadIdx.x, n = blockIdx.x;
  if (t < 16) Ew[t] = E[n*16 + t];
  __syncthreads();
  if (t < 64){
    float a = 0.f;
    #pragma unroll
    for (int e=0;e<16;e++) a += Ew[e]*ub[e*64 + t];
    bnu[t] = a;
  }
  for (int idx=t; idx<8448; idx+=256){
    int o = idx & 63, rest = idx>>6, i = rest % 66, k = rest / 66;
    float a = 0.f;
    #pragma unroll
    for (int e=0;e<16;e++) a += Ew[e]*uw[((e*2+k)*66 + i)*64 + o];
    Wn[k][i][o] = a;
  }
  __syncthreads();
  for (int bb=0; bb<4; ++bb){
    for (int idx=t; idx<528; idx+=256){
      int bi = idx/132, rem = idx%132, k = rem/66, i = rem%66;
      int b = bb*4 + bi;
      float v;
      if (k==0) v = (i<2) ? x[((size_t)b*2048+n)*2 + i] : zs[((size_t)b*2048+n)*64 + (i-2)];
      else      v = (i<2) ? c1x[((size_t)b*2048+n)*2 + i] : c2s[((size_t)b*2048+n)*64 + (i-2)];
      xg4[bi][k][i] = v;
    }
    __syncthreads();
    {
      int bi = t>>6, o = t&63, b = bb*4 + bi;
      float a = 0.f;
      #pragma unroll
      for (int k=0;k<2;k++)
        for (int i=0;i<66;i++) a += xg4[bi][k][i]*Wn[k][i][o];
      float hc = tanhf(a + bnu[o]);
      float rv = rws[((size_t)b*2048+n)*64 + o];
      h[((size_t)b*2048+n)*64 + o] = rv*state[((size_t)b*2048+n)*64 + o] + (1.f - rv)*hc;
    }
    __syncthreads();
  }
}

// ---------------------------------------------------------------------------
// sm_step2 (R15): both n-halves' online-softmax steps fused — 2x ILP on the
// serial fmax/shfl chains, and ht fragments loaded ONCE per kt (R14 loaded
// them twice, once per sm_step call). Math identical per nh.
// ---------------------------------------------------------------------------
static __device__ __forceinline__ void sm_step2(
    f32x16& L00, f32x16& L10, f32x16& L01, f32x16& L11,
    f32x16& oA0, f32x16& oA1, f32x16& oB0, f32x16& oB1,
    float& mrun0, float& srun0, float& mrun1, float& srun1,
    const u8* __restrict__ htb, int ktA, int ktB, int lane, int h32){
  const float LN256 = 5.545177444479562f;
  float c0 = L00[0], c1 = L01[0];
  #pragma unroll
  for (int g=1; g<16; ++g){ c0 = fmaxf(c0, L00[g]); c1 = fmaxf(c1, L01[g]); }
  #pragma unroll
  for (int g=0; g<16; ++g){ c0 = fmaxf(c0, L10[g]); c1 = fmaxf(c1, L11[g]); }
  c0 = fmaxf(c0, __shfl_xor(c0, 32));
  c1 = fmaxf(c1, __shfl_xor(c1, 32));
  float mnew0 = fmaxf(mrun0, 0.5f*c0);
  float mnew1 = fmaxf(mrun1, 0.5f*c1);
  float sc0 = __expf(mrun0 - mnew0);
  float sc1 = __expf(mrun1 - mnew1);
  srun0 *= sc0; srun1 *= sc1;
  #pragma unroll
  for (int g=0; g<16; ++g){
    const int rowl = (g&3) + 8*(g>>2) + 4*h32;
    float f0 = __shfl(sc0, rowl);
    float f1 = __shfl(sc1, rowl);
    oA0[g] *= f0; oA1[g] *= f0;
    oB0[g] *= f1; oB1[g] *= f1;
  }
  float cs0 = 0.f, cs1 = 0.f;
  #pragma unroll
  for (int kti=0; kti<2; ++kti){
    const int kt = kti ? ktB : ktA;
    long h00 = *(const long*)(htb + (size_t)((kt*2+0)*2 + 0)*512 + lane*8);
    long h01 = *(const long*)(htb + (size_t)((kt*2+0)*2 + 1)*512 + lane*8);
    long h10 = *(const long*)(htb + (size_t)((kt*2+1)*2 + 0)*512 + lane*8);
    long h11 = *(const long*)(htb + (size_t)((kt*2+1)*2 + 1)*512 + lane*8);
    float p0[16], p1[16];
    #pragma unroll
    for (int g=0; g<16; ++g){
      float La = kti ? L10[g] : L00[g];
      float Lb = kti ? L11[g] : L01[g];
      p0[g] = __expf(0.5f*La - mnew0 + LN256);   // 256-scaled
      p1[g] = __expf(0.5f*Lb - mnew1 + LN256);
      cs0 += p0[g]; cs1 += p1[g];
    }
    u32 qA0 = pk4_fp8(p0[0],p0[1],p0[2],p0[3]);
    u32 qB0 = pk4_fp8(p0[4],p0[5],p0[6],p0[7]);
    u32 qC0 = pk4_fp8(p0[8],p0[9],p0[10],p0[11]);
    u32 qD0 = pk4_fp8(p0[12],p0[13],p0[14],p0[15]);
    u32 qA1 = pk4_fp8(p1[0],p1[1],p1[2],p1[3]);
    u32 qB1 = pk4_fp8(p1[4],p1[5],p1[6],p1[7]);
    u32 qC1 = pk4_fp8(p1[8],p1[9],p1[10],p1[11]);
    u32 qD1 = pk4_fp8(p1[12],p1[13],p1[14],p1[15]);
    u32 xA0 = __shfl_xor(qA0,32), xB0 = __shfl_xor(qB0,32);
    u32 xC0 = __shfl_xor(qC0,32), xD0 = __shfl_xor(qD0,32);
    u32 xA1 = __shfl_xor(qA1,32), xB1 = __shfl_xor(qB1,32);
    u32 xC1 = __shfl_xor(qC1,32), xD1 = __shfl_xor(qD1,32);
    long pf00 = h32 ? mklong(xB0,qB0) : mklong(qA0,xA0);
    long pf01 = h32 ? mklong(xD0,qD0) : mklong(qC0,xC0);
    long pf10 = h32 ? mklong(xB1,qB1) : mklong(qA1,xA1);
    long pf11 = h32 ? mklong(xD1,qD1) : mklong(qC1,xC1);
    oA0 = mfma_fp8_32(pf00, h00, oA0);
    oA1 = mfma_fp8_32(pf00, h01, oA1);
    oB0 = mfma_fp8_32(pf10, h00, oB0);
    oB1 = mfma_fp8_32(pf10, h01, oB1);
    oA0 = mfma_fp8_32(pf01, h10, oA0);
    oA1 = mfma_fp8_32(pf01, h11, oA1);
    oB0 = mfma_fp8_32(pf11, h10, oB0);
    oB1 = mfma_fp8_32(pf11, h11, oB1);
  }
  cs0 += __shfl_xor(cs0, 32);
  cs1 += __shfl_xor(cs1, 32);
  srun0 += cs0; srun1 += cs1;
  mrun0 = mnew0; mrun1 = mnew1;
}

// ---------------------------------------------------------------------------
// K5: fused degrees — R15: R14 structure (wave = 64 n-rows x 256 k-cols,
// W tiled once per block) + fused sm_step2. p0 rotation + setprio kept.
// ---------------------------------------------------------------------------
#define SROW8 2056

__global__ void __launch_bounds__(512,2) k_deg(
    const u32* __restrict__ mbits, const u16* __restrict__ hb16,
    const u8* __restrict__ W8,
    const u8* __restrict__ ht8p, const u16* __restrict__ hfm,
    const float* __restrict__ hf32, const float* __restrict__ oc_in,
    float* __restrict__ outp, int fin){
  extern __shared__ u8 S[];
  __shared__ float maxw[64][8];
  __shared__ float sumw[64][8];
  __shared__ float sgl_lds[64];
  const int t = threadIdx.x;
  const int w = t >> 6, lane = t & 63, lc = lane & 15, q = lane >> 4;
  const int l32 = lane & 31, h32 = lane >> 5;
  const int id = blockIdx.x;
  const int b = id >> 5, n0 = (id & 31) * 64;
  const int p0 = (id >> 3) & 31;          // per-CU-within-XCD rotation offset
  const u32* mrow0 = mbits + (size_t)(n0 >> 5)*2048;
  const u32* mrow1 = mrow0 + 2048;
  const u16* hbb = hb16 + (size_t)b*2048*64;
  const u16* hfb = hfm + (size_t)b*131072;
  const u8* htb = ht8p + (size_t)b*131072;

  // ---- phase 1: S[r][m] = fp8( (bit ? h_n.h_m : 0) / 8 ), 64 rows ----
  {
    const int c0 = p0 & 15;
    bf16x8 A[4][2];
    #pragma unroll
    for (int rt=0; rt<4; ++rt)
      #pragma unroll
      for (int ks=0; ks<2; ++ks)
        A[rt][ks] = *(const bf16x8*)&hbb[(size_t)(n0 + rt*16 + lc)*64 + ks*32 + q*8];
    int ctg0 = w*16 + c0;
    bf16x8 B0c = *(const bf16x8*)(hfb + (size_t)ctg0*512 + lane*8);
    bf16x8 B1c = *(const bf16x8*)(hfb + 65536 + (size_t)ctg0*512 + lane*8);
    u32 m0c = mrow0[ctg0*16 + lc], m1c = mrow1[ctg0*16 + lc];
    #pragma unroll 1
    for (int ct=0; ct<16; ++ct){
      const int ctg  = w*16 + ((ct + c0) & 15);
      const int ctgn = w*16 + ((ct + 1 + c0) & 15);
      bf16x8 B0n = *(const bf16x8*)(hfb + (size_t)ctgn*512 + lane*8);
      bf16x8 B1n = *(const bf16x8*)(hfb + 65536 + (size_t)ctgn*512 + lane*8);
      u32 m0n = mrow0[ctgn*16 + lc], m1n = mrow1[ctgn*16 + lc];
      const int mcol = ctg*16 + lc;
      f32x4 a[4];
      #pragma unroll
      for (int rt=0; rt<4; ++rt){
        a[rt] = (f32x4){0.f,0.f,0.f,0.f};
        a[rt] = mfma_bf16(A[rt][0], B0c, a[rt]);
        a[rt] = mfma_bf16(A[rt][1], B1c, a[rt]);
      }
      #pragma unroll
      for (int rt=0; rt<4; ++rt){
        const u32 mw = (rt < 2) ? m0c : m1c;
        #pragma unroll
        for (int i=0;i<4;i++){
          const int row = rt*16 + q*4 + i;
          float v = ((mw >> (row & 31)) & 1u) ? a[rt][i]*0.125f : 0.f;
          S[row*SROW8 + mcol] = f2fp8(v);
        }
      }
      B0c = B0n; B1c = B1n; m0c = m0n; m1c = m1n;
    }
  }
  __syncthreads();

  // ---- fused phases 2+3+4: wave w owns k-cols [w*256,(w+1)*256), all 64 n ----
  const u8* sb0 = S + (size_t)l32*SROW8 + h32*8;          // nh0 rows
  const u8* sb1 = S + (size_t)(32 + l32)*SROW8 + h32*8;   // nh1 rows
  const u8* wl = W8 + lane*16;
  f32x16 oA0 = (f32x16)(0.f), oA1 = (f32x16)(0.f);        // nh0: dt0, dt1
  f32x16 oB0 = (f32x16)(0.f), oB1 = (f32x16)(0.f);        // nh1
  float mrun0 = -1e30f, srun0 = 0.f, mrun1 = -1e30f, srun1 = 0.f;
  #pragma unroll 1
  for (int si = 0; si < 4; ++si){
    const int ktA = w*8 + si*2, ktB = ktA + 1;
    f32x16 L00 = (f32x16)(0.f), L01 = (f32x16)(0.f);      // kti0: nh0, nh1
    f32x16 L10 = (f32x16)(0.f), L11 = (f32x16)(0.f);      // kti1
    uint4 wv0, wv1, wv2, wv3;
    {
      const int pt0 = p0;
      wv0 = *(const uint4*)(wl + (size_t)((pt0*64 + ktA)*2 + 0)*1024);
      wv1 = *(const uint4*)(wl + (size_t)((pt0*64 + ktA)*2 + 1)*1024);
      wv2 = *(const uint4*)(wl + (size_t)((pt0*64 + ktB)*2 + 0)*1024);
      wv3 = *(const uint4*)(wl + (size_t)((pt0*64 + ktB)*2 + 1)*1024);
    }
    __builtin_amdgcn_s_setprio(1);
    #pragma unroll 1
    for (int pti = 0; pti < 32; ++pti){
      const int pt  = (pti + p0) & 31;
      const int ptn = (pti + 1 + p0) & 31;
      long b00 = *(const long*)(sb0 + pt*64 +  0);
      long b01 = *(const long*)(sb0 + pt*64 + 16);
      long b02 = *(const long*)(sb0 + pt*64 + 32);
      long b03 = *(const long*)(sb0 + pt*64 + 48);
      long b10 = *(const long*)(sb1 + pt*64 +  0);
      long b11 = *(const long*)(sb1 + pt*64 + 16);
      long b12 = *(const long*)(sb1 + pt*64 + 32);
      long b13 = *(const long*)(sb1 + pt*64 + 48);
      uint4 wn0 = *(const uint4*)(wl + (size_t)((ptn*64 + ktA)*2 + 0)*1024);
      uint4 wn1 = *(const uint4*)(wl + (size_t)((ptn*64 + ktA)*2 + 1)*1024);
      uint4 wn2 = *(const uint4*)(wl + (size_t)((ptn*64 + ktB)*2 + 0)*1024);
      uint4 wn3 = *(const uint4*)(wl + (size_t)((ptn*64 + ktB)*2 + 1)*1024);
      L00 = mfma_fp8_32(lo64(wv0), b00, L00);
      L01 = mfma_fp8_32(lo64(wv0), b10, L01);
      L10 = mfma_fp8_32(lo64(wv2), b00, L10);
      L11 = mfma_fp8_32(lo64(wv2), b10, L11);
      L00 = mfma_fp8_32(hi64(wv0), b01, L00);
      L01 = mfma_fp8_32(hi64(wv0), b11, L01);
      L10 = mfma_fp8_32(hi64(wv2), b01, L10);
      L11 = mfma_fp8_32(hi64(wv2), b11, L11);
      L00 = mfma_fp8_32(lo64(wv1), b02, L00);
      L01 = mfma_fp8_32(lo64(wv1), b12, L01);
      L10 = mfma_fp8_32(lo64(wv3), b02, L10);
      L11 = mfma_fp8_32(lo64(wv3), b12, L11);
      L00 = mfma_fp8_32(hi64(wv1), b03, L00);
      L01 = mfma_fp8_32(hi64(wv1), b13, L01);
      L10 = mfma_fp8_32(hi64(wv3), b03, L10);
      L11 = mfma_fp8_32(hi64(wv3), b13, L11);
      wv0 = wn0; wv1 = wn1; wv2 = wn2; wv3 = wn3;
    }
    __builtin_amdgcn_s_setprio(0);
    sm_step2(L00, L10, L01, L11, oA0, oA1, oB0, oB1,
             mrun0, srun0, mrun1, srun1, htb, ktA, ktB, lane, h32);
  }

  // ---- merge: log-sum-exp combine of 8 k-slices ----
  if (h32 == 0){
    maxw[l32][w] = mrun0;      sumw[l32][w] = srun0;
    maxw[32 + l32][w] = mrun1; sumw[32 + l32][w] = srun1;
  }
  __syncthreads();                        // all S reads done; max/sum visible
  float* scr = (float*)S;
  {
    float m_g0 = maxw[l32][0];
    #pragma unroll
    for (int j=1;j<8;j++) m_g0 = fmaxf(m_g0, maxw[l32][j]);
    float s_g0 = 0.f;
    #pragma unroll
    for (int j=0;j<8;j++) s_g0 += sumw[l32][j]*__expf(maxw[l32][j]-m_g0);
    float m_g1 = maxw[32+l32][0];
    #pragma unroll
    for (int j=1;j<8;j++) m_g1 = fmaxf(m_g1, maxw[32+l32][j]);
    float s_g1 = 0.f;
    #pragma unroll
    for (int j=0;j<8;j++) s_g1 += sumw[32+l32][j]*__expf(maxw[32+l32][j]-m_g1);
    if (w == 0 && h32 == 0){
      sgl_lds[l32] = s_g0;
      sgl_lds[32 + l32] = s_g1;
    }
    float f0 = __expf(mrun0 - m_g0);
    float f1 = __expf(mrun1 - m_g1);
    #pragma unroll
    for (int g=0; g<16; ++g){
      const int rowl = (g&3) + 8*(g>>2) + 4*h32;
      float fr0 = __shfl(f0, rowl);
      float fr1 = __shfl(f1, rowl);
      scr[((size_t)w*64 + rowl)*64 + l32]           = oA0[g]*fr0;
      scr[((size_t)w*64 + rowl)*64 + 32 + l32]      = oA1[g]*fr0;
      scr[((size_t)w*64 + 32 + rowl)*64 + l32]      = oB0[g]*fr1;
      scr[((size_t)w*64 + 32 + rowl)*64 + 32 + l32] = oB1[g]*fr1;
    }
  }
  __syncthreads();

  // ---- reduce 8 partials + epilogue ----
  {
    const int n_g = t >> 3, d0 = (t & 7)*8;
    const float sdiv = sgl_lds[n_g];
    float* op = outp + (size_t)b*2048*64;
    const float* hp = hf32 + (size_t)b*2048*64;
    const float* cp = oc_in + (size_t)b*2048*64;
    #pragma unroll
    for (int j=0;j<8;j++){
      const int d = d0 + j;
      float v = 0.f;
      #pragma unroll
      for (int qq=0; qq<8; ++qq)
        v += scr[((size_t)qq*64 + n_g)*64 + d];
      v /= sdiv;
      size_t idx = (size_t)(n0 + n_g)*64 + d;
      if (fin) v = 0.8f*hp[idx] - 0.1f*cp[idx] + 0.1f*v;
      op[idx] = v;
    }
  }
}

// ---------------------------------------------------------------------------
extern "C" void kernel_launch(void* const* d_in, const int* in_sizes, int n_in,
                              void* d_out, int out_size, void* d_ws, size_t ws_size,
                              hipStream_t stream) {
  const float* x     = (const float*)d_in[0];
  const float* state = (const float*)d_in[1];
  const float* E     = (const float*)d_in[2];
  const float* Wc    = (const float*)d_in[3];
  const float* Wd    = (const float*)d_in[4];
  const float* gw    = (const float*)d_in[5];
  const float* gb    = (const float*)d_in[6];
  const float* uw    = (const float*)d_in[7];
  const float* ub    = (const float*)d_in[8];

  // workspace layout (bytes). Total 73,662,464 B = 70.2 MB.
  char* base = (char*)d_ws;
  u16*   P    = (u16*)(base + 0);           //  8,388,608  (dead after 2nd k_conv)
  u32*   mp2  = (u32*)(base + 0);           //    524,288  (aliases P; written after P dead)
  u32*   mn2  = (u32*)(base + 524288);      //    524,288  (aliases P)
  u8*    msk  = (u8*) (base + 8388608);     //  4,194,304
  u8*    Wc8  = (u8*) (base + 12582912);    //  4,194,304
  u8*    Wd8  = (u8*) (base + 16777216);    //  4,194,304
  u16*   hb16 = (u16*)(base + 20971520);    //  4,194,304
  u8*    ht8p = (u8*) (base + 25165824);    //  2,097,152
  u16*   hfm  = (u16*)(base + 27262976);    //  4,194,304
  float* c1x  = (float*)(base + 31457280);  //    262,144
  float* c1s  = (float*)(base + 31719424);  //  8,388,608
  float* zs   = (float*)(base + 40108032);  //  8,388,608
  float* rws  = (float*)(base + 48496640);  //  8,388,608
  float* c2s  = (float*)(base + 56885248);  //  8,388,608
  float* h    = (float*)(base + 65273856);  //  8,388,608
  float* oc   = c1s;                        // dead after k_gate

  k_w8<<<dim3(32,32,2), 256, 0, stream>>>(Wc, Wd, Wc8, Wd8);
  k_P<<<2048, 256, 0, stream>>>(E, P, msk);
  k_conv<<<dim3(32,16), 256, 0, stream>>>(P, state, c1s, x, c1x, 1);   // + c1x fused
  k_gate<<<2048, 256, 0, stream>>>(E, gw, gb, x, state, c1x, c1s, zs, rws);
  k_conv<<<dim3(32,16), 256, 0, stream>>>(P, zs, c2s, x, c1x, 0);
  k_upd<<<2048, 256, 0, stream>>>(E, uw, ub, x, state, zs, c1x, c2s, rws, h);
  k_hcvt<<<dim3(32,16), 256, 0, stream>>>(h, hb16, ht8p, hfm);
  k_mbits<<<dim3(32,8), 256, 0, stream>>>(msk, mp2, mn2);   // P dead by now

  const int deg_lds = 64*SROW8;   // 131,584 B dynamic (+~4.3 KB static)
  hipFuncSetAttribute((const void*)k_deg, hipFuncAttributeMaxDynamicSharedMemorySize, deg_lds);
  // dispatch 1: connect mask — only Wc8 hot in every XCD L2
  k_deg<<<512, 512, deg_lds, stream>>>(mp2, hb16, Wc8, ht8p, hfm, h, h, oc, 0);
  // dispatch 2: disconnect mask — only Wd8 hot; fused final epilogue -> d_out
  k_deg<<<512, 512, deg_lds, stream>>>(mn2, hb16, Wd8, ht8p, hfm, h, oc, (float*)d_out, 1);
}